// Round 1
// baseline (735.283 us; speedup 1.0000x reference)
//
#include <hip/hip_runtime.h>
#include <stdint.h>

typedef __attribute__((ext_vector_type(8))) short short8;
typedef __attribute__((ext_vector_type(4))) float f32x4;

__device__ __forceinline__ float bf2f(unsigned short s) {
  return __uint_as_float(((unsigned)s) << 16);
}
__device__ __forceinline__ unsigned short f2bf(float f) {
  unsigned u = __float_as_uint(f);
  u += 0x7fffu + ((u >> 16) & 1u);   // round-to-nearest-even
  return (unsigned short)(u >> 16);
}

// ---------------- CSR build ----------------
__global__ void gs_count_deg(const int* __restrict__ dst, int* __restrict__ cnt, int E) {
  int e = blockIdx.x * 256 + threadIdx.x;
  if (e < E) atomicAdd(&cnt[dst[e]], 1);
}

// 3-phase scan: A) per-1024-chunk local exclusive scan + chunk sum
__global__ void gs_scanA(const int* __restrict__ cnt, int* __restrict__ rp,
                         int* __restrict__ bsum, int n) {
  __shared__ int sm[256];
  const int b = blockIdx.x, t = threadIdx.x;
  const int base = b * 1024 + t * 4;
  int v[4]; int s = 0;
#pragma unroll
  for (int i = 0; i < 4; ++i) { v[i] = (base + i < n) ? cnt[base + i] : 0; s += v[i]; }
  sm[t] = s;
  __syncthreads();
  for (int off = 1; off < 256; off <<= 1) {
    int x = (t >= off) ? sm[t - off] : 0;
    __syncthreads();
    sm[t] += x;
    __syncthreads();
  }
  int run = sm[t] - s;
#pragma unroll
  for (int i = 0; i < 4; ++i) { if (base + i < n) rp[base + i] = run; run += v[i]; }
  if (t == 255) bsum[b] = sm[255];
}

// B) serial scan of chunk sums (~20 entries), total stored at bsum[nb]
__global__ void gs_scanB(int* bsum, int nb) {
  if (threadIdx.x == 0 && blockIdx.x == 0) {
    int run = 0;
    for (int i = 0; i < nb; ++i) { int v = bsum[i]; bsum[i] = run; run += v; }
    bsum[nb] = run;
  }
}

// C) add chunk offsets, replicate into cur, set rp[n]
__global__ void gs_scanC(int* __restrict__ rp, int* __restrict__ cur,
                         const int* __restrict__ bsum, int n, int nb) {
  int i = blockIdx.x * 256 + threadIdx.x;
  if (i < n) {
    int v = rp[i] + bsum[i >> 10];
    rp[i] = v;
    cur[i] = v;
  }
  if (i == n) rp[n] = bsum[nb];
}

__global__ void gs_fill_csr(const int* __restrict__ src, const int* __restrict__ dst,
                            int* __restrict__ cur, int* __restrict__ col, int E) {
  int e = blockIdx.x * 256 + threadIdx.x;
  if (e < E) {
    int pos = atomicAdd(&cur[dst[e]], 1);
    col[pos] = src[e];
  }
}

// ---------------- conversions / weight packing ----------------
__global__ void gs_f32_to_bf16(const float* __restrict__ in, unsigned short* __restrict__ out, int n4) {
  int i = blockIdx.x * 256 + threadIdx.x;
  if (i < n4) {
    float4 f = ((const float4*)in)[i];
    ushort4 o;
    o.x = f2bf(f.x); o.y = f2bf(f.y); o.z = f2bf(f.z); o.w = f2bf(f.w);
    ((ushort4*)out)[i] = o;
  }
}

// batched tiled transpose-pack: W [K x F] fp32 row-major -> WT [F x K] bf16 row-major
struct TP { const float* W; unsigned short* WT; int K, F; };
struct TP8 { TP t[8]; };

__global__ void gs_tpack8(TP8 args) {
  const TP a = args.t[blockIdx.z];
  const int k0 = blockIdx.x * 32, f0 = blockIdx.y * 32;
  if (k0 >= a.K || f0 >= a.F) return;
  __shared__ float t[32][33];
  const int tx = threadIdx.x, ty = threadIdx.y;
#pragma unroll
  for (int r = ty; r < 32; r += 8) {
    int k = k0 + r, f = f0 + tx;
    t[r][tx] = (k < a.K && f < a.F) ? a.W[(size_t)k * a.F + f] : 0.f;
  }
  __syncthreads();
#pragma unroll
  for (int r = ty; r < 32; r += 8) {
    int f = f0 + r, k = k0 + tx;
    if (f < a.F && k < a.K) a.WT[(size_t)f * a.K + k] = f2bf(t[tx][r]);
  }
}

// ---------------- sliced fused aggregation ----------------
// block = (node v, 128-col slice). 64 threads, ushort2/lane (256 B row footprint).
// Slice-major dispatch keeps the co-resident gather footprint ~N*256B (~5 MB)
// so the deg/8 per-XCD reuse lands in L2 instead of L3.
// o = mean_{nb} C[nb, c0:c0+128] (+ C[v, zoff+c0 ...] if zoff>=0) (+bias) (relu?)
__global__ __launch_bounds__(64)
void gs_agg_slice(const unsigned short* __restrict__ C, int ldc, int zoff,
                  const int* __restrict__ rp, const int* __restrict__ col,
                  const float* __restrict__ bias,
                  unsigned short* __restrict__ hout, float* __restrict__ fout,
                  int F, int relu) {
  const int v = blockIdx.x;
  const int cc = blockIdx.y * 128 + 2 * threadIdx.x;
  const int l = threadIdx.x;
  const int s0 = rp[v], s1 = rp[v + 1];
  const float inv = 1.0f / (float)max(s1 - s0, 1);
  float a0 = 0.f, a1 = 0.f;
  __shared__ int nb[64];
  for (int base = s0; base < s1; base += 64) {
    int m = min(s1 - base, 64);
    __syncthreads();
    if (l < m) nb[l] = col[base + l];
    __syncthreads();
    int j = 0;
    for (; j + 4 <= m; j += 4) {
      ushort2 u0 = *(const ushort2*)(C + (size_t)nb[j + 0] * ldc + cc);
      ushort2 u1 = *(const ushort2*)(C + (size_t)nb[j + 1] * ldc + cc);
      ushort2 u2 = *(const ushort2*)(C + (size_t)nb[j + 2] * ldc + cc);
      ushort2 u3 = *(const ushort2*)(C + (size_t)nb[j + 3] * ldc + cc);
      a0 += bf2f(u0.x) + bf2f(u1.x) + bf2f(u2.x) + bf2f(u3.x);
      a1 += bf2f(u0.y) + bf2f(u1.y) + bf2f(u2.y) + bf2f(u3.y);
    }
    for (; j < m; ++j) {
      ushort2 u = *(const ushort2*)(C + (size_t)nb[j] * ldc + cc);
      a0 += bf2f(u.x); a1 += bf2f(u.y);
    }
  }
  float o0 = a0 * inv, o1 = a1 * inv;
  if (zoff >= 0) {
    ushort2 u = *(const ushort2*)(C + (size_t)v * ldc + zoff + cc);
    o0 += bf2f(u.x); o1 += bf2f(u.y);
  }
  if (bias) { o0 += bias[cc]; o1 += bias[cc + 1]; }
  if (relu) { o0 = fmaxf(o0, 0.f); o1 = fmaxf(o1, 0.f); }
  if (hout) {
    ushort2 u; u.x = f2bf(o0); u.y = f2bf(o1);
    *(ushort2*)(hout + (size_t)v * F + cc) = u;
  }
  if (fout) *(float2*)(fout + (size_t)v * F + cc) = make_float2(o0, o1);
}

// ---------------- GEMM: C = act(A1@B1^T [+ A2@B2^T] + bias) ----------------
// 256x256 tile, BK=64, 8 waves (2M x 4N), 512 threads. 8-phase counted-vmcnt
// schedule (m201 template): per phase {12 ds_read_b128 | stage 1 half-tile via
// 2x global_load_lds | raw s_barrier | lgkmcnt(0)+sched_barrier | setprio(1)
// 16 MFMA setprio(0) | [vmcnt(4) at ph4/ph8] | s_barrier}. LDS 128 KiB:
// 2 dbuf x 2 halves x [128x64] x {A,B}. Halves are laid out by quadrant-of-use
// (A: row bit6 == mh; B: col bit5 == nh) so each half-region is dead one phase
// before its re-stage. XOR swizzle (chunk ^= row&7) applied on the pre-swizzled
// GLOBAL source + on the ds_read address (both-sides involution, rule #21).
// Tail: stages past nt re-read the last K-tile (clamped source, dead data) so
// the per-wave vmcnt window arithmetic is identical in every iteration.
// Requires Nn%256==0, K%128==0. M arbitrary (row clamp; OOB rows not stored).
#define GLL(SRC, DST) __builtin_amdgcn_global_load_lds(                        \
    (const __attribute__((address_space(1))) unsigned int*)(SRC),              \
    (__attribute__((address_space(3))) unsigned int*)(DST), 16, 0, 0)

#define PHASE(T, MH, NH, ST_T, ST_B, ST_H, DO_VM)                              \
  {                                                                            \
    const int buf_ = (T) & 1;                                                  \
    const unsigned short* Ab_ = &lA[buf_][MH][0];                              \
    const unsigned short* Bb_ = &lB[buf_][NH][0];                              \
    short8 aF_[4][2], bF_[2][2];                                               \
    _Pragma("unroll")                                                          \
    for (int fi = 0; fi < 4; ++fi) {                                           \
      int lra = wMl + fi * 16;                                                 \
      _Pragma("unroll")                                                        \
      for (int ks = 0; ks < 2; ++ks) {                                         \
        int ch = (ks * 4 + qk) ^ (lra & 7);                                    \
        aF_[fi][ks] = *(const short8*)&Ab_[lra * 64 + ch * 8];                 \
      }                                                                        \
    }                                                                          \
    _Pragma("unroll")                                                          \
    for (int fj = 0; fj < 2; ++fj) {                                           \
      int lrb = wNl + fj * 16;                                                 \
      _Pragma("unroll")                                                        \
      for (int ks = 0; ks < 2; ++ks) {                                         \
        int ch = (ks * 4 + qk) ^ (lrb & 7);                                    \
        bF_[fj][ks] = *(const short8*)&Bb_[lrb * 64 + ch * 8];                 \
      }                                                                        \
    }                                                                          \
    STAGE(ST_T, ST_B, ST_H);                                                   \
    __builtin_amdgcn_s_barrier();                                              \
    asm volatile("s_waitcnt lgkmcnt(0)" ::: "memory");                         \
    __builtin_amdgcn_sched_barrier(0);                                         \
    __builtin_amdgcn_s_setprio(1);                                             \
    _Pragma("unroll")                                                          \
    for (int fi = 0; fi < 4; ++fi)                                             \
      _Pragma("unroll")                                                        \
      for (int fj = 0; fj < 2; ++fj)                                           \
        _Pragma("unroll")                                                      \
        for (int ks = 0; ks < 2; ++ks)                                         \
          acc[MH][fi][NH][fj] = __builtin_amdgcn_mfma_f32_16x16x32_bf16(       \
              aF_[fi][ks], bF_[fj][ks], acc[MH][fi][NH][fj], 0, 0, 0);         \
    __builtin_amdgcn_s_setprio(0);                                             \
    if (DO_VM) asm volatile("s_waitcnt vmcnt(4)" ::: "memory");                \
    __builtin_amdgcn_s_barrier();                                              \
  }

__global__ __launch_bounds__(512, 2)
void gs_gemm(const unsigned short* __restrict__ A1, const unsigned short* __restrict__ A2,
             const unsigned short* __restrict__ B1, const unsigned short* __restrict__ B2,
             const float* __restrict__ bias, unsigned short* __restrict__ Hout,
             int M, int Nn, int K, int doRelu, int Mt, int Nt) {
  __shared__ unsigned short lA[2][2][8192];   // [buf][half][128*64]
  __shared__ unsigned short lB[2][2][8192];
  const int tid = threadIdx.x;
  const int wid = tid >> 6;
  const int lane = tid & 63;

  // 1-D grid swizzled: groups of MG M-tiles sweep all N-tiles (A stays L2-hot)
  const int MG = 8;
  const int per = MG * Nt;
  const int g = blockIdx.x / per;
  const int rem = blockIdx.x - g * per;
  const int gsz = min(MG, Mt - g * MG);
  const int nIdx = rem / gsz;
  const int mIdx = g * MG + (rem - nIdx * gsz);
  const int bM = mIdx * 256;
  const int bN = nIdx * 256;

  const int wM_ = wid >> 2;                 // 0..1 (M half of tile)
  const int wN_ = wid & 3;                  // 0..3 (N quarter)
  const int qk  = lane >> 4;                // K-subchunk of fragment
  const int wMl = wM_ * 64 + (lane & 15);   // A local row base in half-region
  const int wNl = wN_ * 32 + (lane & 15);   // B local row base in half-region

  // staging geometry: thread covers chunks tid and 512+tid of a half-tile
  // (chunk = 16B; half-tile = [128 local rows][64 K] = 1024 chunks)
  const int lr  = tid >> 3;                                // local row, chunk1
  const int swk = ((tid & 7) ^ (lr & 7)) * 8;              // swizzled src K-chunk (ushorts)
  const int rB0 = (lr >> 5) * 64 + (lr & 31);              // B global-row part

  const int kt = K / 64;                    // K-tiles per pass
  const int nt = A2 ? 2 * kt : kt;          // total K-tiles (always even)
  const int NI = nt / 2;

  f32x4 acc[2][4][2][2];
#pragma unroll
  for (int a = 0; a < 2; ++a)
#pragma unroll
    for (int b = 0; b < 4; ++b)
#pragma unroll
      for (int c = 0; c < 2; ++c)
#pragma unroll
        for (int d = 0; d < 2; ++d) acc[a][b][c][d] = (f32x4){0.f, 0.f, 0.f, 0.f};

  auto STAGE = [&](int t, int isB, int h) {
    const int tc = (t < nt) ? t : (nt - 1);    // clamped source (tail: dead data)
    const int pass = (tc >= kt) ? 1 : 0;
    const int k0 = (tc - pass * kt) * 64;
    const int buf = t & 1;
    if (!isB) {
      const unsigned short* Ap = pass ? A2 : A1;
      int r1 = bM + h * 64 + lr;          // half h holds rows with bit6==h
      int r2 = r1 + 128;
      if (r1 >= M) r1 = M - 1;
      if (r2 >= M) r2 = M - 1;
      char* d = (char*)&lA[buf][h][0] + wid * 1024;
      GLL(Ap + (size_t)r1 * K + k0 + swk, d);
      GLL(Ap + (size_t)r2 * K + k0 + swk, d + 8192);
    } else {
      const unsigned short* Bp = pass ? B2 : B1;
      int r1 = bN + h * 32 + rB0;         // half h holds cols with bit5==h
      char* d = (char*)&lB[buf][h][0] + wid * 1024;
      GLL(Bp + (size_t)r1 * K + k0 + swk, d);
      GLL(Bp + (size_t)(r1 + 128) * K + k0 + swk, d + 8192);
    }
  };

  // prologue: t0 complete + t1.{A0,B0}; wait t0 landed (last 2 half-tiles may fly)
  STAGE(0, 0, 0); STAGE(0, 1, 0); STAGE(0, 0, 1); STAGE(0, 1, 1);
  STAGE(1, 0, 0); STAGE(1, 1, 0);
  asm volatile("s_waitcnt vmcnt(4)" ::: "memory");
  __builtin_amdgcn_s_barrier();

  for (int i = 0; i < NI; ++i) {
    const int t0 = 2 * i, t1 = t0 + 1, t2 = t0 + 2, t3 = t0 + 3;
    PHASE(t0, 0, 0, t1, 0, 1, 0)   // stage t1.A1 (region dead since prev ph8)
    PHASE(t0, 0, 1, t1, 1, 1, 0)   // stage t1.B1
    PHASE(t0, 1, 0, t2, 0, 0, 0)   // stage t2.A0 (dead after ph2)
    PHASE(t0, 1, 1, t2, 1, 0, 1)   // stage t2.B0; vmcnt(4): t1 fully landed
    PHASE(t1, 0, 0, t2, 0, 1, 0)   // stage t2.A1
    PHASE(t1, 0, 1, t2, 1, 1, 0)   // stage t2.B1
    PHASE(t1, 1, 0, t3, 0, 0, 0)   // stage t3.A0
    PHASE(t1, 1, 1, t3, 1, 0, 1)   // stage t3.B0; vmcnt(4): t2 fully landed
  }

  // C/D layout: col = lane&15, row = (lane>>4)*4 + reg   [m89/m91]
#pragma unroll
  for (int mh = 0; mh < 2; ++mh)
#pragma unroll
    for (int fi = 0; fi < 4; ++fi) {
      const int row0 = bM + wM_ * 128 + mh * 64 + fi * 16 + (lane >> 4) * 4;
#pragma unroll
      for (int r = 0; r < 4; ++r) {
        const int row = row0 + r;
        if (row >= M) continue;
#pragma unroll
        for (int nh = 0; nh < 2; ++nh)
#pragma unroll
          for (int fj = 0; fj < 2; ++fj) {
            const int colN = bN + wN_ * 64 + nh * 32 + fj * 16 + (lane & 15);
            float v = acc[mh][fi][nh][fj][r];
            if (bias) v += bias[colN];
            if (doRelu) v = fmaxf(v, 0.f);
            Hout[(size_t)row * Nn + colN] = f2bf(v);
          }
      }
    }
}

// ---------------- layer 5 ----------------
// yz[v, 0:5] = h4[v]@Wl5, yz[v, 5:10] = h4[v]@Wr5   (fp32)
__global__ __launch_bounds__(64)
void gs_l5dot(const unsigned short* __restrict__ h4, const float* __restrict__ Wl,
              const float* __restrict__ Wr, float* __restrict__ yz) {
  __shared__ float sW[2560];
  const int v = blockIdx.x;
  const int l = threadIdx.x;
  for (int i = l; i < 2560; i += 64) sW[i] = (i < 1280) ? Wl[i] : Wr[i - 1280];
  __syncthreads();
  ushort4 u = ((const ushort4*)(h4 + (size_t)v * 256))[l];   // k = 4l..4l+3
  float hv[4] = {bf2f(u.x), bf2f(u.y), bf2f(u.z), bf2f(u.w)};
  float acc[10];
#pragma unroll
  for (int n = 0; n < 10; ++n) acc[n] = 0.f;
#pragma unroll
  for (int t = 0; t < 4; ++t) {
    int k = 4 * l + t;
#pragma unroll
    for (int n = 0; n < 5; ++n) {
      acc[n] += hv[t] * sW[k * 5 + n];
      acc[5 + n] += hv[t] * sW[1280 + k * 5 + n];
    }
  }
#pragma unroll
  for (int n = 0; n < 10; ++n)
    for (int off = 32; off > 0; off >>= 1) acc[n] += __shfl_down(acc[n], off, 64);
  if (l == 0) {
#pragma unroll
    for (int n = 0; n < 10; ++n) yz[(size_t)v * 10 + n] = acc[n];
  }
}

// out[v] = mean_{nb} y5[nb] + z5[v] + b  (no relu)
__global__ __launch_bounds__(64)
void gs_l5agg(const float* __restrict__ yz, const int* __restrict__ rp,
              const int* __restrict__ col, const float* __restrict__ b,
              float* __restrict__ out) {
  const int v = blockIdx.x;
  const int l = threadIdx.x;
  const int s0 = rp[v], s1 = rp[v + 1];
  const float inv = 1.0f / (float)max(s1 - s0, 1);
  float acc[5] = {0.f, 0.f, 0.f, 0.f, 0.f};
  for (int e = s0 + l; e < s1; e += 64) {
    const float* yr = yz + (size_t)col[e] * 10;
#pragma unroll
    for (int n = 0; n < 5; ++n) acc[n] += yr[n];
  }
#pragma unroll
  for (int n = 0; n < 5; ++n)
    for (int off = 32; off > 0; off >>= 1) acc[n] += __shfl_down(acc[n], off, 64);
  if (l == 0) {
#pragma unroll
    for (int n = 0; n < 5; ++n)
      out[(size_t)v * 5 + n] = acc[n] * inv + yz[(size_t)v * 10 + 5 + n] + b[n];
  }
}

// ---------------- launcher ----------------
extern "C" void kernel_launch(void* const* d_in, const int* in_sizes, int n_in,
                              void* d_out, int out_size, void* d_ws, size_t ws_size,
                              hipStream_t stream) {
  const float* x = (const float*)d_in[0];
  const int* ei = (const int*)d_in[1];
  const int N = in_sizes[0] / 768;
  const int E = in_sizes[1] / 2;
  const int* src = ei;
  const int* dst = ei + E;

  const float* Wl[5];
  const float* Wr[5];
  const float* bb[5];
  for (int l = 0; l < 5; ++l) {
    Wl[l] = (const float*)d_in[2 + 3 * l];
    Wr[l] = (const float*)d_in[3 + 3 * l];
    bb[l] = (const float*)d_in[4 + 3 * l];
  }

  char* w = (char*)d_ws;
  size_t off = 0;
  auto take = [&](size_t bytes) -> char* {
    char* p = w + off;
    off = (off + bytes + 255) & ~(size_t)255;
    return p;
  };
  // arenas (aliased over layer lifetime)
  unsigned short* ar1 = (unsigned short*)take((size_t)N * 768 * 2);   // xb -> C3
  unsigned short* ar2 = (unsigned short*)take((size_t)N * 768 * 2);   // aggb -> h2
  unsigned short* ar3 = (unsigned short*)take((size_t)N * 1536 * 2);  // h1 -> C4|h3|h4|yz5
  unsigned short* C2  = (unsigned short*)take((size_t)N * 1536 * 2);
  int* cnt  = (int*)take((size_t)N * 4);
  int* rp   = (int*)take((size_t)(N + 1) * 4);
  int* cur  = (int*)take((size_t)N * 4);
  int* col  = (int*)take((size_t)E * 4);
  const int nbChunks = (N + 1023) / 1024;
  int* bsum = (int*)take((size_t)(nbChunks + 1) * 4);
  unsigned short* WT1l = (unsigned short*)take((size_t)1536 * 768 * 2);
  unsigned short* WT1r = (unsigned short*)take((size_t)1536 * 768 * 2);
  unsigned short* WT2  = (unsigned short*)take((size_t)1536 * 1536 * 2);
  unsigned short* WT3  = (unsigned short*)take((size_t)768 * 768 * 2);
  unsigned short* WT4  = (unsigned short*)take((size_t)512 * 384 * 2);

  unsigned short* xb   = ar1;
  unsigned short* C3   = ar1;
  unsigned short* aggb = ar2;
  unsigned short* h2   = ar2;
  unsigned short* h1   = ar3;
  unsigned short* C4   = ar3;                                  // N x 512
  unsigned short* h3   = ar3 + (size_t)N * 512;                // N x 384
  unsigned short* h4   = ar3 + (size_t)N * (512 + 384);        // N x 256
  float*          yz5  = (float*)(ar3 + (size_t)N * (512 + 384 + 256)); // N x 10 f32

  const int M = N;
  const int Mt = (M + 255) / 256;          // 256-row tiles for the 8-phase GEMM

  // CSR build
  hipMemsetAsync(cnt, 0, (size_t)N * 4, stream);
  gs_count_deg<<<(E + 255) / 256, 256, 0, stream>>>(dst, cnt, E);
  gs_scanA<<<nbChunks, 256, 0, stream>>>(cnt, rp, bsum, N);
  gs_scanB<<<1, 64, 0, stream>>>(bsum, nbChunks);
  gs_scanC<<<(N + 256) / 256, 256, 0, stream>>>(rp, cur, bsum, N, nbChunks);
  gs_fill_csr<<<(E + 255) / 256, 256, 0, stream>>>(src, dst, cur, col, E);

  // conversions (all coalesced); batched transpose-pack (1 launch)
  gs_f32_to_bf16<<<((N * 768 / 4) + 255) / 256, 256, 0, stream>>>(x, xb, N * 768 / 4);
  TP8 tp;
  tp.t[0] = {Wl[0], WT1l, 768, 1536};
  tp.t[1] = {Wr[0], WT1r, 768, 1536};
  tp.t[2] = {Wl[1], WT2, 1536, 768};
  tp.t[3] = {Wr[1], WT2 + (size_t)768 * 1536, 1536, 768};
  tp.t[4] = {Wl[2], WT3, 768, 384};
  tp.t[5] = {Wr[2], WT3 + (size_t)384 * 768, 768, 384};
  tp.t[6] = {Wl[3], WT4, 384, 256};
  tp.t[7] = {Wr[3], WT4 + (size_t)256 * 384, 384, 256};
  gs_tpack8<<<dim3(48, 48, 8), dim3(32, 8), 0, stream>>>(tp);

  float* houtF = (float*)d_out;                 // [N,256] fp32
  float* out5  = (float*)d_out + (size_t)N * 256;

  // L1: agg-before (Fin 768 < Fout 1536), dual GEMM -> h1 (relu+bias)
  gs_agg_slice<<<dim3(N, 6), 64, 0, stream>>>(xb, 768, -1, rp, col, nullptr, aggb, nullptr, 768, 0);
  gs_gemm<<<Mt * 6, 512, 0, stream>>>(aggb, xb, WT1l, WT1r, bb[0], h1, M, 1536, 768, 1, Mt, 6);

  // L2: GEMM C2 = h1 @ [Wl2|Wr2]  (N x 1536), fused sliced agg over 768 -> h2
  gs_gemm<<<Mt * 6, 512, 0, stream>>>(h1, nullptr, WT2, nullptr, nullptr, C2, M, 1536, 1536, 0, Mt, 6);
  gs_agg_slice<<<dim3(N, 6), 64, 0, stream>>>(C2, 1536, 768, rp, col, bb[1], h2, nullptr, 768, 1);

  // L3: GEMM C3 = h2 @ [Wl3|Wr3]  (N x 768), fused sliced agg over 384 -> h3
  gs_gemm<<<Mt * 3, 512, 0, stream>>>(h2, nullptr, WT3, nullptr, nullptr, C3, M, 768, 768, 0, Mt, 3);
  gs_agg_slice<<<dim3(N, 3), 64, 0, stream>>>(C3, 768, 384, rp, col, bb[2], h3, nullptr, 384, 1);

  // L4: GEMM C4 = h3 @ [Wl4|Wr4]  (N x 512), fused sliced agg over 256 -> h4 (bf16) + d_out (fp32)
  gs_gemm<<<Mt * 2, 512, 0, stream>>>(h3, nullptr, WT4, nullptr, nullptr, C4, M, 512, 384, 0, Mt, 2);
  gs_agg_slice<<<dim3(N, 2), 64, 0, stream>>>(C4, 512, 256, rp, col, bb[3], h4, houtF, 256, 1);

  // L5: per-node dot -> yz5 [N,10] fp32, then tiny agg over 5 -> out
  gs_l5dot<<<N, 64, 0, stream>>>(h4, Wl[4], Wr[4], yz5);
  gs_l5agg<<<N, 64, 0, stream>>>(yz5, rp, col, bb[4], out5);
}

// Round 2
// 696.862 us; speedup vs baseline: 1.0551x; 1.0551x over previous
//
#include <hip/hip_runtime.h>
#include <stdint.h>

typedef __attribute__((ext_vector_type(8))) short short8;
typedef __attribute__((ext_vector_type(4))) float f32x4;

__device__ __forceinline__ float bf2f(unsigned short s) {
  return __uint_as_float(((unsigned)s) << 16);
}
__device__ __forceinline__ unsigned short f2bf(float f) {
  unsigned u = __float_as_uint(f);
  u += 0x7fffu + ((u >> 16) & 1u);   // round-to-nearest-even
  return (unsigned short)(u >> 16);
}

// ---------------- CSR build ----------------
__global__ void gs_count_deg(const int* __restrict__ dst, int* __restrict__ cnt, int E) {
  int e = blockIdx.x * 256 + threadIdx.x;
  if (e < E) atomicAdd(&cnt[dst[e]], 1);
}

// 3-phase scan: A) per-1024-chunk local exclusive scan + chunk sum
__global__ void gs_scanA(const int* __restrict__ cnt, int* __restrict__ rp,
                         int* __restrict__ bsum, int n) {
  __shared__ int sm[256];
  const int b = blockIdx.x, t = threadIdx.x;
  const int base = b * 1024 + t * 4;
  int v[4]; int s = 0;
#pragma unroll
  for (int i = 0; i < 4; ++i) { v[i] = (base + i < n) ? cnt[base + i] : 0; s += v[i]; }
  sm[t] = s;
  __syncthreads();
  for (int off = 1; off < 256; off <<= 1) {
    int x = (t >= off) ? sm[t - off] : 0;
    __syncthreads();
    sm[t] += x;
    __syncthreads();
  }
  int run = sm[t] - s;
#pragma unroll
  for (int i = 0; i < 4; ++i) { if (base + i < n) rp[base + i] = run; run += v[i]; }
  if (t == 255) bsum[b] = sm[255];
}

// B) serial scan of chunk sums (~20 entries), total stored at bsum[nb]
__global__ void gs_scanB(int* bsum, int nb) {
  if (threadIdx.x == 0 && blockIdx.x == 0) {
    int run = 0;
    for (int i = 0; i < nb; ++i) { int v = bsum[i]; bsum[i] = run; run += v; }
    bsum[nb] = run;
  }
}

// C) add chunk offsets, replicate into cur, set rp[n]
__global__ void gs_scanC(int* __restrict__ rp, int* __restrict__ cur,
                         const int* __restrict__ bsum, int n, int nb) {
  int i = blockIdx.x * 256 + threadIdx.x;
  if (i < n) {
    int v = rp[i] + bsum[i >> 10];
    rp[i] = v;
    cur[i] = v;
  }
  if (i == n) rp[n] = bsum[nb];
}

__global__ void gs_fill_csr(const int* __restrict__ src, const int* __restrict__ dst,
                            int* __restrict__ cur, int* __restrict__ col, int E) {
  int e = blockIdx.x * 256 + threadIdx.x;
  if (e < E) {
    int pos = atomicAdd(&cur[dst[e]], 1);
    col[pos] = src[e];
  }
}

// ---------------- conversions / weight packing ----------------
__global__ void gs_f32_to_bf16(const float* __restrict__ in, unsigned short* __restrict__ out, int n4) {
  int i = blockIdx.x * 256 + threadIdx.x;
  if (i < n4) {
    float4 f = ((const float4*)in)[i];
    ushort4 o;
    o.x = f2bf(f.x); o.y = f2bf(f.y); o.z = f2bf(f.z); o.w = f2bf(f.w);
    ((ushort4*)out)[i] = o;
  }
}

// batched tiled transpose-pack: W [K x F] fp32 row-major -> WT [F x K] bf16 row-major
struct TP { const float* W; unsigned short* WT; int K, F; };
struct TP8 { TP t[8]; };

__global__ void gs_tpack8(TP8 args) {
  const TP a = args.t[blockIdx.z];
  const int k0 = blockIdx.x * 32, f0 = blockIdx.y * 32;
  if (k0 >= a.K || f0 >= a.F) return;
  __shared__ float t[32][33];
  const int tx = threadIdx.x, ty = threadIdx.y;
#pragma unroll
  for (int r = ty; r < 32; r += 8) {
    int k = k0 + r, f = f0 + tx;
    t[r][tx] = (k < a.K && f < a.F) ? a.W[(size_t)k * a.F + f] : 0.f;
  }
  __syncthreads();
#pragma unroll
  for (int r = ty; r < 32; r += 8) {
    int f = f0 + r, k = k0 + tx;
    if (f < a.F && k < a.K) a.WT[(size_t)f * a.K + k] = f2bf(t[tx][r]);
  }
}

// ---------------- sliced fused aggregation ----------------
// block = (node v, 128-col slice). 64 threads, ushort2/lane (256 B row footprint).
// Slice-major dispatch keeps the co-resident gather footprint ~N*256B (~5 MB)
// so the deg/8 per-XCD reuse lands in L2 instead of L3.
// o = mean_{nb} C[nb, c0:c0+128] (+ C[v, zoff+c0 ...] if zoff>=0) (+bias) (relu?)
__global__ __launch_bounds__(64)
void gs_agg_slice(const unsigned short* __restrict__ C, int ldc, int zoff,
                  const int* __restrict__ rp, const int* __restrict__ col,
                  const float* __restrict__ bias,
                  unsigned short* __restrict__ hout, float* __restrict__ fout,
                  int F, int relu) {
  const int v = blockIdx.x;
  const int cc = blockIdx.y * 128 + 2 * threadIdx.x;
  const int l = threadIdx.x;
  const int s0 = rp[v], s1 = rp[v + 1];
  const float inv = 1.0f / (float)max(s1 - s0, 1);
  float a0 = 0.f, a1 = 0.f;
  __shared__ int nb[64];
  for (int base = s0; base < s1; base += 64) {
    int m = min(s1 - base, 64);
    __syncthreads();
    if (l < m) nb[l] = col[base + l];
    __syncthreads();
    int j = 0;
    for (; j + 4 <= m; j += 4) {
      ushort2 u0 = *(const ushort2*)(C + (size_t)nb[j + 0] * ldc + cc);
      ushort2 u1 = *(const ushort2*)(C + (size_t)nb[j + 1] * ldc + cc);
      ushort2 u2 = *(const ushort2*)(C + (size_t)nb[j + 2] * ldc + cc);
      ushort2 u3 = *(const ushort2*)(C + (size_t)nb[j + 3] * ldc + cc);
      a0 += bf2f(u0.x) + bf2f(u1.x) + bf2f(u2.x) + bf2f(u3.x);
      a1 += bf2f(u0.y) + bf2f(u1.y) + bf2f(u2.y) + bf2f(u3.y);
    }
    for (; j < m; ++j) {
      ushort2 u = *(const ushort2*)(C + (size_t)nb[j] * ldc + cc);
      a0 += bf2f(u.x); a1 += bf2f(u.y);
    }
  }
  float o0 = a0 * inv, o1 = a1 * inv;
  if (zoff >= 0) {
    ushort2 u = *(const ushort2*)(C + (size_t)v * ldc + zoff + cc);
    o0 += bf2f(u.x); o1 += bf2f(u.y);
  }
  if (bias) { o0 += bias[cc]; o1 += bias[cc + 1]; }
  if (relu) { o0 = fmaxf(o0, 0.f); o1 = fmaxf(o1, 0.f); }
  if (hout) {
    ushort2 u; u.x = f2bf(o0); u.y = f2bf(o1);
    *(ushort2*)(hout + (size_t)v * F + cc) = u;
  }
  if (fout) *(float2*)(fout + (size_t)v * F + cc) = make_float2(o0, o1);
}

// ---------------- GEMM: C = act(A1@B1^T [+ A2@B2^T] + bias) ----------------
// 256x256 tile, BK=64, 8 waves (2M x 4N), 512 threads. 8-phase counted-vmcnt
// schedule (m201 template) with REGISTER-RESIDENT fragments (R1 fix: each
// fragment is ds_read ONCE per K-tile and reused across quadrant phases —
// 24 b128 reads/wave/K-tile, template parity; the R0 port re-read per phase
// = 48 reads and was LDS-bound at MfmaUtil 25%).
// Per K-tile (4 phases): ph1 reads A0+B0 (12 reads), ph2 reads B1 (4),
// ph3 reads A1 (8), ph4 reads nothing (pure MFMA). Each phase stages one
// half-tile via 2x global_load_lds; vmcnt(4) only at ph4/ph8.
// LDS 128 KiB: 2 dbuf x 2 halves x [128x64] x {A,B}; halves laid out by
// quadrant-of-use (A: row bit6; B: col bit5) so each region is dead at least
// one phase before its re-stage (reads only moved EARLIER vs R0 => still safe).
// XOR swizzle (chunk ^= row&7) on pre-swizzled GLOBAL source + ds_read addr
// (both-sides involution, rule #21). Tail stages clamp source (dead data) so
// the per-wave vmcnt window is identical every iteration.
// Requires Nn%256==0, K%128==0. M arbitrary (row clamp; OOB rows not stored).
#define GLL(SRC, DST) __builtin_amdgcn_global_load_lds(                        \
    (const __attribute__((address_space(1))) unsigned int*)(SRC),              \
    (__attribute__((address_space(3))) unsigned int*)(DST), 16, 0, 0)

#define PHASE(T, MH, NH, RD_A, RD_B, ST_T, ST_B, ST_H, DO_VM)                  \
  {                                                                            \
    const int buf_ = (T) & 1;                                                  \
    if (RD_A) {                                                                \
      const unsigned short* Ab_ = &lA[buf_][MH][0];                            \
      _Pragma("unroll")                                                        \
      for (int fi = 0; fi < 4; ++fi) {                                         \
        int lra = wMl + fi * 16;                                               \
        _Pragma("unroll")                                                      \
        for (int ks = 0; ks < 2; ++ks) {                                       \
          int ch = (ks * 4 + qk) ^ (lra & 7);                                  \
          rA[fi][ks] = *(const short8*)&Ab_[lra * 64 + ch * 8];                \
        }                                                                      \
      }                                                                        \
    }                                                                          \
    if (RD_B) {                                                                \
      const unsigned short* Bb_ = &lB[buf_][NH][0];                            \
      _Pragma("unroll")                                                        \
      for (int fj = 0; fj < 2; ++fj) {                                         \
        int lrb = wNl + fj * 16;                                               \
        _Pragma("unroll")                                                      \
        for (int ks = 0; ks < 2; ++ks) {                                       \
          int ch = (ks * 4 + qk) ^ (lrb & 7);                                  \
          rB[NH][fj][ks] = *(const short8*)&Bb_[lrb * 64 + ch * 8];            \
        }                                                                      \
      }                                                                        \
    }                                                                          \
    STAGE(ST_T, ST_B, ST_H);                                                   \
    __builtin_amdgcn_s_barrier();                                              \
    asm volatile("s_waitcnt lgkmcnt(0)" ::: "memory");                         \
    __builtin_amdgcn_sched_barrier(0);                                         \
    __builtin_amdgcn_s_setprio(1);                                             \
    _Pragma("unroll")                                                          \
    for (int fi = 0; fi < 4; ++fi)                                             \
      _Pragma("unroll")                                                        \
      for (int fj = 0; fj < 2; ++fj)                                           \
        _Pragma("unroll")                                                      \
        for (int ks = 0; ks < 2; ++ks)                                         \
          acc[MH][fi][NH][fj] = __builtin_amdgcn_mfma_f32_16x16x32_bf16(       \
              rA[fi][ks], rB[NH][fj][ks], acc[MH][fi][NH][fj], 0, 0, 0);       \
    __builtin_amdgcn_s_setprio(0);                                             \
    if (DO_VM) asm volatile("s_waitcnt vmcnt(4)" ::: "memory");                \
    __builtin_amdgcn_s_barrier();                                              \
  }

__global__ __launch_bounds__(512, 2)
void gs_gemm(const unsigned short* __restrict__ A1, const unsigned short* __restrict__ A2,
             const unsigned short* __restrict__ B1, const unsigned short* __restrict__ B2,
             const float* __restrict__ bias, unsigned short* __restrict__ Hout,
             int M, int Nn, int K, int doRelu, int Mt, int Nt) {
  __shared__ unsigned short lA[2][2][8192];   // [buf][half][128*64]
  __shared__ unsigned short lB[2][2][8192];
  const int tid = threadIdx.x;
  const int wid = tid >> 6;
  const int lane = tid & 63;

  // 1-D grid swizzled: groups of MG M-tiles sweep all N-tiles (A stays L2-hot)
  const int MG = 8;
  const int per = MG * Nt;
  const int g = blockIdx.x / per;
  const int rem = blockIdx.x - g * per;
  const int gsz = min(MG, Mt - g * MG);
  const int nIdx = rem / gsz;
  const int mIdx = g * MG + (rem - nIdx * gsz);
  const int bM = mIdx * 256;
  const int bN = nIdx * 256;

  const int wM_ = wid >> 2;                 // 0..1 (M half of tile)
  const int wN_ = wid & 3;                  // 0..3 (N quarter)
  const int qk  = lane >> 4;                // K-subchunk of fragment
  const int wMl = wM_ * 64 + (lane & 15);   // A local row base in half-region
  const int wNl = wN_ * 32 + (lane & 15);   // B local row base in half-region

  // staging geometry: thread covers chunks tid and 512+tid of a half-tile
  // (chunk = 16B; half-tile = [128 local rows][64 K] = 1024 chunks)
  const int lr  = tid >> 3;                                // local row, chunk1
  const int swk = ((tid & 7) ^ (lr & 7)) * 8;              // swizzled src K-chunk (ushorts)
  const int rB0 = (lr >> 5) * 64 + (lr & 31);              // B global-row part

  const int kt = K / 64;                    // K-tiles per pass
  const int nt = A2 ? 2 * kt : kt;          // total K-tiles (always even)
  const int NI = nt / 2;

  f32x4 acc[2][4][2][2];
#pragma unroll
  for (int a = 0; a < 2; ++a)
#pragma unroll
    for (int b = 0; b < 4; ++b)
#pragma unroll
      for (int c = 0; c < 2; ++c)
#pragma unroll
        for (int d = 0; d < 2; ++d) acc[a][b][c][d] = (f32x4){0.f, 0.f, 0.f, 0.f};

  // register-resident fragments (static indexing only — rule #20)
  short8 rA[4][2];        // A frags of current M-half
  short8 rB[2][2][2];     // B frags of both N-halves [nh][fj][ks]

  auto STAGE = [&](int t, int isB, int h) {
    const int tc = (t < nt) ? t : (nt - 1);    // clamped source (tail: dead data)
    const int pass = (tc >= kt) ? 1 : 0;
    const int k0 = (tc - pass * kt) * 64;
    const int buf = t & 1;
    if (!isB) {
      const unsigned short* Ap = pass ? A2 : A1;
      int r1 = bM + h * 64 + lr;          // half h holds rows with bit6==h
      int r2 = r1 + 128;
      if (r1 >= M) r1 = M - 1;
      if (r2 >= M) r2 = M - 1;
      char* d = (char*)&lA[buf][h][0] + wid * 1024;
      GLL(Ap + (size_t)r1 * K + k0 + swk, d);
      GLL(Ap + (size_t)r2 * K + k0 + swk, d + 8192);
    } else {
      const unsigned short* Bp = pass ? B2 : B1;
      int r1 = bN + h * 32 + rB0;         // half h holds cols with bit5==h
      char* d = (char*)&lB[buf][h][0] + wid * 1024;
      GLL(Bp + (size_t)r1 * K + k0 + swk, d);
      GLL(Bp + (size_t)(r1 + 128) * K + k0 + swk, d + 8192);
    }
  };

  // prologue: t0 complete + t1.{A0,B0}; wait t0 landed (last 2 half-tiles may fly)
  STAGE(0, 0, 0); STAGE(0, 1, 0); STAGE(0, 0, 1); STAGE(0, 1, 1);
  STAGE(1, 0, 0); STAGE(1, 1, 0);
  asm volatile("s_waitcnt vmcnt(4)" ::: "memory");
  __builtin_amdgcn_s_barrier();

  for (int i = 0; i < NI; ++i) {
    const int t0 = 2 * i, t1 = t0 + 1, t2 = t0 + 2, t3 = t0 + 3;
    PHASE(t0, 0, 0, 1, 1, t1, 0, 1, 0)   // rd A0+B0; stage t1.A1 (dead region)
    PHASE(t0, 0, 1, 0, 1, t1, 1, 1, 0)   // rd B1;    stage t1.B1
    PHASE(t0, 1, 0, 1, 0, t2, 0, 0, 0)   // rd A1;    stage t2.A0 (dead after ph1)
    PHASE(t0, 1, 1, 0, 0, t2, 1, 0, 1)   // pure MFMA; stage t2.B0; vmcnt(4): t1 landed
    PHASE(t1, 0, 0, 1, 1, t2, 0, 1, 0)
    PHASE(t1, 0, 1, 0, 1, t2, 1, 1, 0)
    PHASE(t1, 1, 0, 1, 0, t3, 0, 0, 0)
    PHASE(t1, 1, 1, 0, 0, t3, 1, 0, 1)   // vmcnt(4): t2 landed
  }

  // C/D layout: col = lane&15, row = (lane>>4)*4 + reg   [m89/m91]
#pragma unroll
  for (int mh = 0; mh < 2; ++mh)
#pragma unroll
    for (int fi = 0; fi < 4; ++fi) {
      const int row0 = bM + wM_ * 128 + mh * 64 + fi * 16 + (lane >> 4) * 4;
#pragma unroll
      for (int r = 0; r < 4; ++r) {
        const int row = row0 + r;
        if (row >= M) continue;
#pragma unroll
        for (int nh = 0; nh < 2; ++nh)
#pragma unroll
          for (int fj = 0; fj < 2; ++fj) {
            const int colN = bN + wN_ * 64 + nh * 32 + fj * 16 + (lane & 15);
            float v = acc[mh][fi][nh][fj][r];
            if (bias) v += bias[colN];
            if (doRelu) v = fmaxf(v, 0.f);
            Hout[(size_t)row * Nn + colN] = f2bf(v);
          }
      }
    }
}

// ---------------- layer 5 ----------------
// yz[v, 0:5] = h4[v]@Wl5, yz[v, 5:10] = h4[v]@Wr5   (fp32)
__global__ __launch_bounds__(64)
void gs_l5dot(const unsigned short* __restrict__ h4, const float* __restrict__ Wl,
              const float* __restrict__ Wr, float* __restrict__ yz) {
  __shared__ float sW[2560];
  const int v = blockIdx.x;
  const int l = threadIdx.x;
  for (int i = l; i < 2560; i += 64) sW[i] = (i < 1280) ? Wl[i] : Wr[i - 1280];
  __syncthreads();
  ushort4 u = ((const ushort4*)(h4 + (size_t)v * 256))[l];   // k = 4l..4l+3
  float hv[4] = {bf2f(u.x), bf2f(u.y), bf2f(u.z), bf2f(u.w)};
  float acc[10];
#pragma unroll
  for (int n = 0; n < 10; ++n) acc[n] = 0.f;
#pragma unroll
  for (int t = 0; t < 4; ++t) {
    int k = 4 * l + t;
#pragma unroll
    for (int n = 0; n < 5; ++n) {
      acc[n] += hv[t] * sW[k * 5 + n];
      acc[5 + n] += hv[t] * sW[1280 + k * 5 + n];
    }
  }
#pragma unroll
  for (int n = 0; n < 10; ++n)
    for (int off = 32; off > 0; off >>= 1) acc[n] += __shfl_down(acc[n], off, 64);
  if (l == 0) {
#pragma unroll
    for (int n = 0; n < 10; ++n) yz[(size_t)v * 10 + n] = acc[n];
  }
}

// out[v] = mean_{nb} y5[nb] + z5[v] + b  (no relu)
__global__ __launch_bounds__(64)
void gs_l5agg(const float* __restrict__ yz, const int* __restrict__ rp,
              const int* __restrict__ col, const float* __restrict__ b,
              float* __restrict__ out) {
  const int v = blockIdx.x;
  const int l = threadIdx.x;
  const int s0 = rp[v], s1 = rp[v + 1];
  const float inv = 1.0f / (float)max(s1 - s0, 1);
  float acc[5] = {0.f, 0.f, 0.f, 0.f, 0.f};
  for (int e = s0 + l; e < s1; e += 64) {
    const float* yr = yz + (size_t)col[e] * 10;
#pragma unroll
    for (int n = 0; n < 5; ++n) acc[n] += yr[n];
  }
#pragma unroll
  for (int n = 0; n < 5; ++n)
    for (int off = 32; off > 0; off >>= 1) acc[n] += __shfl_down(acc[n], off, 64);
  if (l == 0) {
#pragma unroll
    for (int n = 0; n < 5; ++n)
      out[(size_t)v * 5 + n] = acc[n] * inv + yz[(size_t)v * 10 + 5 + n] + b[n];
  }
}

// ---------------- launcher ----------------
extern "C" void kernel_launch(void* const* d_in, const int* in_sizes, int n_in,
                              void* d_out, int out_size, void* d_ws, size_t ws_size,
                              hipStream_t stream) {
  const float* x = (const float*)d_in[0];
  const int* ei = (const int*)d_in[1];
  const int N = in_sizes[0] / 768;
  const int E = in_sizes[1] / 2;
  const int* src = ei;
  const int* dst = ei + E;

  const float* Wl[5];
  const float* Wr[5];
  const float* bb[5];
  for (int l = 0; l < 5; ++l) {
    Wl[l] = (const float*)d_in[2 + 3 * l];
    Wr[l] = (const float*)d_in[3 + 3 * l];
    bb[l] = (const float*)d_in[4 + 3 * l];
  }

  char* w = (char*)d_ws;
  size_t off = 0;
  auto take = [&](size_t bytes) -> char* {
    char* p = w + off;
    off = (off + bytes + 255) & ~(size_t)255;
    return p;
  };
  // arenas (aliased over layer lifetime)
  unsigned short* ar1 = (unsigned short*)take((size_t)N * 768 * 2);   // xb -> C3
  unsigned short* ar2 = (unsigned short*)take((size_t)N * 768 * 2);   // aggb -> h2
  unsigned short* ar3 = (unsigned short*)take((size_t)N * 1536 * 2);  // h1 -> C4|h3|h4|yz5
  unsigned short* C2  = (unsigned short*)take((size_t)N * 1536 * 2);
  int* cnt  = (int*)take((size_t)N * 4);
  int* rp   = (int*)take((size_t)(N + 1) * 4);
  int* cur  = (int*)take((size_t)N * 4);
  int* col  = (int*)take((size_t)E * 4);
  const int nbChunks = (N + 1023) / 1024;
  int* bsum = (int*)take((size_t)(nbChunks + 1) * 4);
  unsigned short* WT1l = (unsigned short*)take((size_t)1536 * 768 * 2);
  unsigned short* WT1r = (unsigned short*)take((size_t)1536 * 768 * 2);
  unsigned short* WT2  = (unsigned short*)take((size_t)1536 * 1536 * 2);
  unsigned short* WT3  = (unsigned short*)take((size_t)768 * 768 * 2);
  unsigned short* WT4  = (unsigned short*)take((size_t)512 * 384 * 2);

  unsigned short* xb   = ar1;
  unsigned short* C3   = ar1;
  unsigned short* aggb = ar2;
  unsigned short* h2   = ar2;
  unsigned short* h1   = ar3;
  unsigned short* C4   = ar3;                                  // N x 512
  unsigned short* h3   = ar3 + (size_t)N * 512;                // N x 384
  unsigned short* h4   = ar3 + (size_t)N * (512 + 384);        // N x 256
  float*          yz5  = (float*)(ar3 + (size_t)N * (512 + 384 + 256)); // N x 10 f32

  const int M = N;
  const int Mt = (M + 255) / 256;          // 256-row tiles for the 8-phase GEMM

  // CSR build
  hipMemsetAsync(cnt, 0, (size_t)N * 4, stream);
  gs_count_deg<<<(E + 255) / 256, 256, 0, stream>>>(dst, cnt, E);
  gs_scanA<<<nbChunks, 256, 0, stream>>>(cnt, rp, bsum, N);
  gs_scanB<<<1, 64, 0, stream>>>(bsum, nbChunks);
  gs_scanC<<<(N + 256) / 256, 256, 0, stream>>>(rp, cur, bsum, N, nbChunks);
  gs_fill_csr<<<(E + 255) / 256, 256, 0, stream>>>(src, dst, cur, col, E);

  // conversions (all coalesced); batched transpose-pack (1 launch)
  gs_f32_to_bf16<<<((N * 768 / 4) + 255) / 256, 256, 0, stream>>>(x, xb, N * 768 / 4);
  TP8 tp;
  tp.t[0] = {Wl[0], WT1l, 768, 1536};
  tp.t[1] = {Wr[0], WT1r, 768, 1536};
  tp.t[2] = {Wl[1], WT2, 1536, 768};
  tp.t[3] = {Wr[1], WT2 + (size_t)768 * 1536, 1536, 768};
  tp.t[4] = {Wl[2], WT3, 768, 384};
  tp.t[5] = {Wr[2], WT3 + (size_t)384 * 768, 768, 384};
  tp.t[6] = {Wl[3], WT4, 384, 256};
  tp.t[7] = {Wr[3], WT4 + (size_t)256 * 384, 384, 256};
  gs_tpack8<<<dim3(48, 48, 8), dim3(32, 8), 0, stream>>>(tp);

  float* houtF = (float*)d_out;                 // [N,256] fp32
  float* out5  = (float*)d_out + (size_t)N * 256;

  // L1: agg-before (Fin 768 < Fout 1536), dual GEMM -> h1 (relu+bias)
  gs_agg_slice<<<dim3(N, 6), 64, 0, stream>>>(xb, 768, -1, rp, col, nullptr, aggb, nullptr, 768, 0);
  gs_gemm<<<Mt * 6, 512, 0, stream>>>(aggb, xb, WT1l, WT1r, bb[0], h1, M, 1536, 768, 1, Mt, 6);

  // L2: GEMM C2 = h1 @ [Wl2|Wr2]  (N x 1536), fused sliced agg over 768 -> h2
  gs_gemm<<<Mt * 6, 512, 0, stream>>>(h1, nullptr, WT2, nullptr, nullptr, C2, M, 1536, 1536, 0, Mt, 6);
  gs_agg_slice<<<dim3(N, 6), 64, 0, stream>>>(C2, 1536, 768, rp, col, bb[1], h2, nullptr, 768, 1);

  // L3: GEMM C3 = h2 @ [Wl3|Wr3]  (N x 768), fused sliced agg over 384 -> h3
  gs_gemm<<<Mt * 3, 512, 0, stream>>>(h2, nullptr, WT3, nullptr, nullptr, C3, M, 768, 768, 0, Mt, 3);
  gs_agg_slice<<<dim3(N, 3), 64, 0, stream>>>(C3, 768, 384, rp, col, bb[2], h3, nullptr, 384, 1);

  // L4: GEMM C4 = h3 @ [Wl4|Wr4]  (N x 512), fused sliced agg over 256 -> h4 (bf16) + d_out (fp32)
  gs_gemm<<<Mt * 2, 512, 0, stream>>>(h3, nullptr, WT4, nullptr, nullptr, C4, M, 512, 384, 0, Mt, 2);
  gs_agg_slice<<<dim3(N, 2), 64, 0, stream>>>(C4, 512, 256, rp, col, bb[3], h4, houtF, 256, 1);

  // L5: per-node dot -> yz5 [N,10] fp32, then tiny agg over 5 -> out
  gs_l5dot<<<N, 64, 0, stream>>>(h4, Wl[4], Wr[4], yz5);
  gs_l5agg<<<N, 64, 0, stream>>>(yz5, rp, col, bb[4], out5);
}

// Round 3
// 680.924 us; speedup vs baseline: 1.0798x; 1.0234x over previous
//
#include <hip/hip_runtime.h>
#include <stdint.h>

typedef __attribute__((ext_vector_type(8))) short short8;
typedef __attribute__((ext_vector_type(4))) float f32x4;

__device__ __forceinline__ float bf2f(unsigned short s) {
  return __uint_as_float(((unsigned)s) << 16);
}
__device__ __forceinline__ unsigned short f2bf(float f) {
  unsigned u = __float_as_uint(f);
  u += 0x7fffu + ((u >> 16) & 1u);   // round-to-nearest-even
  return (unsigned short)(u >> 16);
}

// ---------------- CSR build ----------------
__global__ void gs_count_deg(const int* __restrict__ dst, int* __restrict__ cnt, int E) {
  int e = blockIdx.x * 256 + threadIdx.x;
  if (e < E) atomicAdd(&cnt[dst[e]], 1);
}

// 3-phase scan: A) per-1024-chunk local exclusive scan + chunk sum
__global__ void gs_scanA(const int* __restrict__ cnt, int* __restrict__ rp,
                         int* __restrict__ bsum, int n) {
  __shared__ int sm[256];
  const int b = blockIdx.x, t = threadIdx.x;
  const int base = b * 1024 + t * 4;
  int v[4]; int s = 0;
#pragma unroll
  for (int i = 0; i < 4; ++i) { v[i] = (base + i < n) ? cnt[base + i] : 0; s += v[i]; }
  sm[t] = s;
  __syncthreads();
  for (int off = 1; off < 256; off <<= 1) {
    int x = (t >= off) ? sm[t - off] : 0;
    __syncthreads();
    sm[t] += x;
    __syncthreads();
  }
  int run = sm[t] - s;
#pragma unroll
  for (int i = 0; i < 4; ++i) { if (base + i < n) rp[base + i] = run; run += v[i]; }
  if (t == 255) bsum[b] = sm[255];
}

// B) serial scan of chunk sums (~20 entries), total stored at bsum[nb]
__global__ void gs_scanB(int* bsum, int nb) {
  if (threadIdx.x == 0 && blockIdx.x == 0) {
    int run = 0;
    for (int i = 0; i < nb; ++i) { int v = bsum[i]; bsum[i] = run; run += v; }
    bsum[nb] = run;
  }
}

// C) add chunk offsets, replicate into cur, set rp[n]
__global__ void gs_scanC(int* __restrict__ rp, int* __restrict__ cur,
                         const int* __restrict__ bsum, int n, int nb) {
  int i = blockIdx.x * 256 + threadIdx.x;
  if (i < n) {
    int v = rp[i] + bsum[i >> 10];
    rp[i] = v;
    cur[i] = v;
  }
  if (i == n) rp[n] = bsum[nb];
}

__global__ void gs_fill_csr(const int* __restrict__ src, const int* __restrict__ dst,
                            int* __restrict__ cur, int* __restrict__ col, int E) {
  int e = blockIdx.x * 256 + threadIdx.x;
  if (e < E) {
    int pos = atomicAdd(&cur[dst[e]], 1);
    col[pos] = src[e];
  }
}

// ---------------- conversions / weight packing ----------------
__global__ void gs_f32_to_bf16(const float* __restrict__ in, unsigned short* __restrict__ out, int n4) {
  int i = blockIdx.x * 256 + threadIdx.x;
  if (i < n4) {
    float4 f = ((const float4*)in)[i];
    ushort4 o;
    o.x = f2bf(f.x); o.y = f2bf(f.y); o.z = f2bf(f.z); o.w = f2bf(f.w);
    ((ushort4*)out)[i] = o;
  }
}

// batched tiled transpose-pack: W [K x F] fp32 row-major -> WT [F x K] bf16 row-major
struct TP { const float* W; unsigned short* WT; int K, F; };
struct TP8 { TP t[8]; };

__global__ void gs_tpack8(TP8 args) {
  const TP a = args.t[blockIdx.z];
  const int k0 = blockIdx.x * 32, f0 = blockIdx.y * 32;
  if (k0 >= a.K || f0 >= a.F) return;
  __shared__ float t[32][33];
  const int tx = threadIdx.x, ty = threadIdx.y;
#pragma unroll
  for (int r = ty; r < 32; r += 8) {
    int k = k0 + r, f = f0 + tx;
    t[r][tx] = (k < a.K && f < a.F) ? a.W[(size_t)k * a.F + f] : 0.f;
  }
  __syncthreads();
#pragma unroll
  for (int r = ty; r < 32; r += 8) {
    int f = f0 + r, k = k0 + tx;
    if (f < a.F && k < a.K) a.WT[(size_t)f * a.K + k] = f2bf(t[tx][r]);
  }
}

// ---------------- sliced fused aggregation ----------------
// block = (node v, 128-col slice). 64 threads, ushort2/lane (256 B row footprint).
// Slice-major dispatch keeps the co-resident gather footprint ~N*256B (~5 MB)
// so the deg/8 per-XCD reuse lands in L2 instead of L3.
// o = mean_{nb} C[nb, c0:c0+128] (+ C[v, zoff+c0 ...] if zoff>=0) (+bias) (relu?)
__global__ __launch_bounds__(64)
void gs_agg_slice(const unsigned short* __restrict__ C, int ldc, int zoff,
                  const int* __restrict__ rp, const int* __restrict__ col,
                  const float* __restrict__ bias,
                  unsigned short* __restrict__ hout, float* __restrict__ fout,
                  int F, int relu) {
  const int v = blockIdx.x;
  const int cc = blockIdx.y * 128 + 2 * threadIdx.x;
  const int l = threadIdx.x;
  const int s0 = rp[v], s1 = rp[v + 1];
  const float inv = 1.0f / (float)max(s1 - s0, 1);
  float a0 = 0.f, a1 = 0.f;
  __shared__ int nb[64];
  for (int base = s0; base < s1; base += 64) {
    int m = min(s1 - base, 64);
    __syncthreads();
    if (l < m) nb[l] = col[base + l];
    __syncthreads();
    int j = 0;
    for (; j + 4 <= m; j += 4) {
      ushort2 u0 = *(const ushort2*)(C + (size_t)nb[j + 0] * ldc + cc);
      ushort2 u1 = *(const ushort2*)(C + (size_t)nb[j + 1] * ldc + cc);
      ushort2 u2 = *(const ushort2*)(C + (size_t)nb[j + 2] * ldc + cc);
      ushort2 u3 = *(const ushort2*)(C + (size_t)nb[j + 3] * ldc + cc);
      a0 += bf2f(u0.x) + bf2f(u1.x) + bf2f(u2.x) + bf2f(u3.x);
      a1 += bf2f(u0.y) + bf2f(u1.y) + bf2f(u2.y) + bf2f(u3.y);
    }
    for (; j < m; ++j) {
      ushort2 u = *(const ushort2*)(C + (size_t)nb[j] * ldc + cc);
      a0 += bf2f(u.x); a1 += bf2f(u.y);
    }
  }
  float o0 = a0 * inv, o1 = a1 * inv;
  if (zoff >= 0) {
    ushort2 u = *(const ushort2*)(C + (size_t)v * ldc + zoff + cc);
    o0 += bf2f(u.x); o1 += bf2f(u.y);
  }
  if (bias) { o0 += bias[cc]; o1 += bias[cc + 1]; }
  if (relu) { o0 = fmaxf(o0, 0.f); o1 = fmaxf(o1, 0.f); }
  if (hout) {
    ushort2 u; u.x = f2bf(o0); u.y = f2bf(o1);
    *(ushort2*)(hout + (size_t)v * F + cc) = u;
  }
  if (fout) *(float2*)(fout + (size_t)v * F + cc) = make_float2(o0, o1);
}

// ---------------- GEMM: C = act(A1@B1^T [+ A2@B2^T] + bias) ----------------
// 256x256 tile, BK=64, 8 waves (2M x 4N), 512 threads. 8-phase counted-vmcnt
// schedule with register-resident fragments (24 b128 reads/wave/K-tile) and
// ONE barrier per phase (R2 fix): reads are plain C++ loads whose deps the
// compiler tracks with fine-grained lgkmcnt, so the mid-phase barrier +
// explicit lgkmcnt(0)+sched_barrier pin (rule-18 applies to INLINE-ASM reads
// only) was pure serialization. Phase = {reads | STAGE | setprio(1) MFMA
// setprio(0) | [vmcnt(4) at ph4/ph8] | s_barrier(asm, memory clobber)}.
// Safety: every ds_read's consuming MFMA is in-phase (reads drained before
// the wave's phase-end barrier); every stage-target region's last reader
// drained >=1 barrier before the GLL issues; vmcnt windows unchanged.
// STAGE addresses: per-thread row*K offsets hoisted out of the loop.
// LDS 128 KiB: 2 dbuf x 2 halves x [128x64] x {A,B}; halves by quadrant-of-use
// (A: row bit6; B: col bit5). XOR swizzle (chunk ^= row&7) on pre-swizzled
// GLOBAL source + ds_read addr (both-sides involution, rule #21). Tail stages
// clamp source (dead data) so the vmcnt window is identical every iteration.
// Requires Nn%256==0, K%128==0. M arbitrary (row clamp; OOB rows not stored).
#define GLL(SRC, DST) __builtin_amdgcn_global_load_lds(                        \
    (const __attribute__((address_space(1))) unsigned int*)(SRC),              \
    (__attribute__((address_space(3))) unsigned int*)(DST), 16, 0, 0)

#define PHASE(T, MH, NH, RD_A, RD_B, ST_T, ST_B, ST_H, DO_VM)                  \
  {                                                                            \
    const int buf_ = (T) & 1;                                                  \
    if (RD_A) {                                                                \
      const unsigned short* Ab_ = &lA[buf_][MH][0];                            \
      _Pragma("unroll")                                                        \
      for (int fi = 0; fi < 4; ++fi) {                                         \
        int lra = wMl + fi * 16;                                               \
        _Pragma("unroll")                                                      \
        for (int ks = 0; ks < 2; ++ks) {                                       \
          int ch = (ks * 4 + qk) ^ (lra & 7);                                  \
          rA[fi][ks] = *(const short8*)&Ab_[lra * 64 + ch * 8];                \
        }                                                                      \
      }                                                                        \
    }                                                                          \
    if (RD_B) {                                                                \
      const unsigned short* Bb_ = &lB[buf_][NH][0];                            \
      _Pragma("unroll")                                                        \
      for (int fj = 0; fj < 2; ++fj) {                                         \
        int lrb = wNl + fj * 16;                                               \
        _Pragma("unroll")                                                      \
        for (int ks = 0; ks < 2; ++ks) {                                       \
          int ch = (ks * 4 + qk) ^ (lrb & 7);                                  \
          rB[NH][fj][ks] = *(const short8*)&Bb_[lrb * 64 + ch * 8];            \
        }                                                                      \
      }                                                                        \
    }                                                                          \
    STAGE(ST_T, ST_B, ST_H);                                                   \
    __builtin_amdgcn_s_setprio(1);                                             \
    _Pragma("unroll")                                                          \
    for (int fi = 0; fi < 4; ++fi)                                             \
      _Pragma("unroll")                                                        \
      for (int fj = 0; fj < 2; ++fj)                                           \
        _Pragma("unroll")                                                      \
        for (int ks = 0; ks < 2; ++ks)                                         \
          acc[MH][fi][NH][fj] = __builtin_amdgcn_mfma_f32_16x16x32_bf16(       \
              rA[fi][ks], rB[NH][fj][ks], acc[MH][fi][NH][fj], 0, 0, 0);       \
    __builtin_amdgcn_s_setprio(0);                                             \
    if (DO_VM) asm volatile("s_waitcnt vmcnt(4)" ::: "memory");                \
    asm volatile("s_barrier" ::: "memory");                                    \
  }

__global__ __launch_bounds__(512, 2)
void gs_gemm(const unsigned short* __restrict__ A1, const unsigned short* __restrict__ A2,
             const unsigned short* __restrict__ B1, const unsigned short* __restrict__ B2,
             const float* __restrict__ bias, unsigned short* __restrict__ Hout,
             int M, int Nn, int K, int doRelu, int Mt, int Nt) {
  __shared__ unsigned short lA[2][2][8192];   // [buf][half][128*64]
  __shared__ unsigned short lB[2][2][8192];
  const int tid = threadIdx.x;
  const int wid = tid >> 6;
  const int lane = tid & 63;

  // 1-D grid swizzled: groups of MG M-tiles sweep all N-tiles (A stays L2-hot)
  const int MG = 8;
  const int per = MG * Nt;
  const int g = blockIdx.x / per;
  const int rem = blockIdx.x - g * per;
  const int gsz = min(MG, Mt - g * MG);
  const int nIdx = rem / gsz;
  const int mIdx = g * MG + (rem - nIdx * gsz);
  const int bM = mIdx * 256;
  const int bN = nIdx * 256;

  const int wM_ = wid >> 2;                 // 0..1 (M half of tile)
  const int wN_ = wid & 3;                  // 0..3 (N quarter)
  const int qk  = lane >> 4;                // K-subchunk of fragment
  const int wMl = wM_ * 64 + (lane & 15);   // A local row base in half-region
  const int wNl = wN_ * 32 + (lane & 15);   // B local row base in half-region

  // staging geometry: thread covers chunks tid and 512+tid of a half-tile
  // (chunk = 16B; half-tile = [128 local rows][64 K] = 1024 chunks)
  const int lr  = tid >> 3;                                // local row, chunk1
  const int swk = ((tid & 7) ^ (lr & 7)) * 8;              // swizzled src K-chunk (ushorts)
  const int rB0 = (lr >> 5) * 64 + (lr & 31);              // B global-row part

  const int kt = K / 64;                    // K-tiles per pass
  const int nt = A2 ? 2 * kt : kt;          // total K-tiles (always even)
  const int NI = nt / 2;

  f32x4 acc[2][4][2][2];
#pragma unroll
  for (int a = 0; a < 2; ++a)
#pragma unroll
    for (int b = 0; b < 4; ++b)
#pragma unroll
      for (int c = 0; c < 2; ++c)
#pragma unroll
        for (int d = 0; d < 2; ++d) acc[a][b][c][d] = (f32x4){0.f, 0.f, 0.f, 0.f};

  // register-resident fragments (static indexing only — rule #20)
  short8 rA[4][2];        // A frags of current M-half
  short8 rB[2][2][2];     // B frags of both N-halves [nh][fj][ks]

  // hoisted per-thread staging offsets (elements): row*K + swizzled chunk
  size_t offA[2][2], offB[2][2];
#pragma unroll
  for (int h = 0; h < 2; ++h) {
    int r1u = bM + h * 64 + lr;
    int r1 = (r1u < M) ? r1u : (M - 1);
    int r2u = r1u + 128;
    int r2 = (r2u < M) ? r2u : (M - 1);
    offA[h][0] = (size_t)r1 * K + swk;
    offA[h][1] = (size_t)r2 * K + swk;
    int rb = bN + h * 32 + rB0;
    offB[h][0] = (size_t)rb * K + swk;
    offB[h][1] = (size_t)(rb + 128) * K + swk;
  }

  auto STAGE = [&](int t, int isB, int h) {
    const int tc = (t < nt) ? t : (nt - 1);    // clamped source (tail: dead data)
    const int pass = (tc >= kt) ? 1 : 0;
    const int k0 = (tc - pass * kt) * 64;      // wave-uniform
    const int buf = t & 1;
    if (!isB) {
      const unsigned short* Ap = (pass ? A2 : A1) + k0;
      char* d = (char*)&lA[buf][h][0] + wid * 1024;
      GLL(Ap + offA[h][0], d);
      GLL(Ap + offA[h][1], d + 8192);
    } else {
      const unsigned short* Bp = (pass ? B2 : B1) + k0;
      char* d = (char*)&lB[buf][h][0] + wid * 1024;
      GLL(Bp + offB[h][0], d);
      GLL(Bp + offB[h][1], d + 8192);
    }
  };

  // prologue: t0 complete + t1.{A0,B0}; wait t0 landed (last 2 half-tiles may fly)
  STAGE(0, 0, 0); STAGE(0, 1, 0); STAGE(0, 0, 1); STAGE(0, 1, 1);
  STAGE(1, 0, 0); STAGE(1, 1, 0);
  asm volatile("s_waitcnt vmcnt(4)" ::: "memory");
  asm volatile("s_barrier" ::: "memory");

  for (int i = 0; i < NI; ++i) {
    const int t0 = 2 * i, t1 = t0 + 1, t2 = t0 + 2, t3 = t0 + 3;
    PHASE(t0, 0, 0, 1, 1, t1, 0, 1, 0)   // rd A0+B0; stage t1.A1 (dead region)
    PHASE(t0, 0, 1, 0, 1, t1, 1, 1, 0)   // rd B1;    stage t1.B1
    PHASE(t0, 1, 0, 1, 0, t2, 0, 0, 0)   // rd A1;    stage t2.A0 (dead after ph1)
    PHASE(t0, 1, 1, 0, 0, t2, 1, 0, 1)   // pure MFMA; stage t2.B0; vmcnt(4): t1 landed
    PHASE(t1, 0, 0, 1, 1, t2, 0, 1, 0)
    PHASE(t1, 0, 1, 0, 1, t2, 1, 1, 0)
    PHASE(t1, 1, 0, 1, 0, t3, 0, 0, 0)
    PHASE(t1, 1, 1, 0, 0, t3, 1, 0, 1)   // vmcnt(4): t2 landed
  }

  // C/D layout: col = lane&15, row = (lane>>4)*4 + reg   [m89/m91]
#pragma unroll
  for (int mh = 0; mh < 2; ++mh)
#pragma unroll
    for (int fi = 0; fi < 4; ++fi) {
      const int row0 = bM + wM_ * 128 + mh * 64 + fi * 16 + (lane >> 4) * 4;
#pragma unroll
      for (int r = 0; r < 4; ++r) {
        const int row = row0 + r;
        if (row >= M) continue;
#pragma unroll
        for (int nh = 0; nh < 2; ++nh)
#pragma unroll
          for (int fj = 0; fj < 2; ++fj) {
            const int colN = bN + wN_ * 64 + nh * 32 + fj * 16 + (lane & 15);
            float v = acc[mh][fi][nh][fj][r];
            if (bias) v += bias[colN];
            if (doRelu) v = fmaxf(v, 0.f);
            Hout[(size_t)row * Nn + colN] = f2bf(v);
          }
      }
    }
}

// ---------------- layer 5 ----------------
// yz[v, 0:5] = h4[v]@Wl5, yz[v, 5:10] = h4[v]@Wr5   (fp32)
__global__ __launch_bounds__(64)
void gs_l5dot(const unsigned short* __restrict__ h4, const float* __restrict__ Wl,
              const float* __restrict__ Wr, float* __restrict__ yz) {
  __shared__ float sW[2560];
  const int v = blockIdx.x;
  const int l = threadIdx.x;
  for (int i = l; i < 2560; i += 64) sW[i] = (i < 1280) ? Wl[i] : Wr[i - 1280];
  __syncthreads();
  ushort4 u = ((const ushort4*)(h4 + (size_t)v * 256))[l];   // k = 4l..4l+3
  float hv[4] = {bf2f(u.x), bf2f(u.y), bf2f(u.z), bf2f(u.w)};
  float acc[10];
#pragma unroll
  for (int n = 0; n < 10; ++n) acc[n] = 0.f;
#pragma unroll
  for (int t = 0; t < 4; ++t) {
    int k = 4 * l + t;
#pragma unroll
    for (int n = 0; n < 5; ++n) {
      acc[n] += hv[t] * sW[k * 5 + n];
      acc[5 + n] += hv[t] * sW[1280 + k * 5 + n];
    }
  }
#pragma unroll
  for (int n = 0; n < 10; ++n)
    for (int off = 32; off > 0; off >>= 1) acc[n] += __shfl_down(acc[n], off, 64);
  if (l == 0) {
#pragma unroll
    for (int n = 0; n < 10; ++n) yz[(size_t)v * 10 + n] = acc[n];
  }
}

// out[v] = mean_{nb} y5[nb] + z5[v] + b  (no relu)
__global__ __launch_bounds__(64)
void gs_l5agg(const float* __restrict__ yz, const int* __restrict__ rp,
              const int* __restrict__ col, const float* __restrict__ b,
              float* __restrict__ out) {
  const int v = blockIdx.x;
  const int l = threadIdx.x;
  const int s0 = rp[v], s1 = rp[v + 1];
  const float inv = 1.0f / (float)max(s1 - s0, 1);
  float acc[5] = {0.f, 0.f, 0.f, 0.f, 0.f};
  for (int e = s0 + l; e < s1; e += 64) {
    const float* yr = yz + (size_t)col[e] * 10;
#pragma unroll
    for (int n = 0; n < 5; ++n) acc[n] += yr[n];
  }
#pragma unroll
  for (int n = 0; n < 5; ++n)
    for (int off = 32; off > 0; off >>= 1) acc[n] += __shfl_down(acc[n], off, 64);
  if (l == 0) {
#pragma unroll
    for (int n = 0; n < 5; ++n)
      out[(size_t)v * 5 + n] = acc[n] * inv + yz[(size_t)v * 10 + 5 + n] + b[n];
  }
}

// ---------------- launcher ----------------
extern "C" void kernel_launch(void* const* d_in, const int* in_sizes, int n_in,
                              void* d_out, int out_size, void* d_ws, size_t ws_size,
                              hipStream_t stream) {
  const float* x = (const float*)d_in[0];
  const int* ei = (const int*)d_in[1];
  const int N = in_sizes[0] / 768;
  const int E = in_sizes[1] / 2;
  const int* src = ei;
  const int* dst = ei + E;

  const float* Wl[5];
  const float* Wr[5];
  const float* bb[5];
  for (int l = 0; l < 5; ++l) {
    Wl[l] = (const float*)d_in[2 + 3 * l];
    Wr[l] = (const float*)d_in[3 + 3 * l];
    bb[l] = (const float*)d_in[4 + 3 * l];
  }

  char* w = (char*)d_ws;
  size_t off = 0;
  auto take = [&](size_t bytes) -> char* {
    char* p = w + off;
    off = (off + bytes + 255) & ~(size_t)255;
    return p;
  };
  // arenas (aliased over layer lifetime)
  unsigned short* ar1 = (unsigned short*)take((size_t)N * 768 * 2);   // xb -> C3
  unsigned short* ar2 = (unsigned short*)take((size_t)N * 768 * 2);   // aggb -> h2
  unsigned short* ar3 = (unsigned short*)take((size_t)N * 1536 * 2);  // h1 -> C4|h3|h4|yz5
  unsigned short* C2  = (unsigned short*)take((size_t)N * 1536 * 2);
  int* cnt  = (int*)take((size_t)N * 4);
  int* rp   = (int*)take((size_t)(N + 1) * 4);
  int* cur  = (int*)take((size_t)N * 4);
  int* col  = (int*)take((size_t)E * 4);
  const int nbChunks = (N + 1023) / 1024;
  int* bsum = (int*)take((size_t)(nbChunks + 1) * 4);
  unsigned short* WT1l = (unsigned short*)take((size_t)1536 * 768 * 2);
  unsigned short* WT1r = (unsigned short*)take((size_t)1536 * 768 * 2);
  unsigned short* WT2  = (unsigned short*)take((size_t)1536 * 1536 * 2);
  unsigned short* WT3  = (unsigned short*)take((size_t)768 * 768 * 2);
  unsigned short* WT4  = (unsigned short*)take((size_t)512 * 384 * 2);

  unsigned short* xb   = ar1;
  unsigned short* C3   = ar1;
  unsigned short* aggb = ar2;
  unsigned short* h2   = ar2;
  unsigned short* h1   = ar3;
  unsigned short* C4   = ar3;                                  // N x 512
  unsigned short* h3   = ar3 + (size_t)N * 512;                // N x 384
  unsigned short* h4   = ar3 + (size_t)N * (512 + 384);        // N x 256
  float*          yz5  = (float*)(ar3 + (size_t)N * (512 + 384 + 256)); // N x 10 f32

  const int M = N;
  const int Mt = (M + 255) / 256;          // 256-row tiles for the 8-phase GEMM

  // CSR build
  hipMemsetAsync(cnt, 0, (size_t)N * 4, stream);
  gs_count_deg<<<(E + 255) / 256, 256, 0, stream>>>(dst, cnt, E);
  gs_scanA<<<nbChunks, 256, 0, stream>>>(cnt, rp, bsum, N);
  gs_scanB<<<1, 64, 0, stream>>>(bsum, nbChunks);
  gs_scanC<<<(N + 256) / 256, 256, 0, stream>>>(rp, cur, bsum, N, nbChunks);
  gs_fill_csr<<<(E + 255) / 256, 256, 0, stream>>>(src, dst, cur, col, E);

  // conversions (all coalesced); batched transpose-pack (1 launch)
  gs_f32_to_bf16<<<((N * 768 / 4) + 255) / 256, 256, 0, stream>>>(x, xb, N * 768 / 4);
  TP8 tp;
  tp.t[0] = {Wl[0], WT1l, 768, 1536};
  tp.t[1] = {Wr[0], WT1r, 768, 1536};
  tp.t[2] = {Wl[1], WT2, 1536, 768};
  tp.t[3] = {Wr[1], WT2 + (size_t)768 * 1536, 1536, 768};
  tp.t[4] = {Wl[2], WT3, 768, 384};
  tp.t[5] = {Wr[2], WT3 + (size_t)384 * 768, 768, 384};
  tp.t[6] = {Wl[3], WT4, 384, 256};
  tp.t[7] = {Wr[3], WT4 + (size_t)256 * 384, 384, 256};
  gs_tpack8<<<dim3(48, 48, 8), dim3(32, 8), 0, stream>>>(tp);

  float* houtF = (float*)d_out;                 // [N,256] fp32
  float* out5  = (float*)d_out + (size_t)N * 256;

  // L1: agg-before (Fin 768 < Fout 1536), dual GEMM -> h1 (relu+bias)
  gs_agg_slice<<<dim3(N, 6), 64, 0, stream>>>(xb, 768, -1, rp, col, nullptr, aggb, nullptr, 768, 0);
  gs_gemm<<<Mt * 6, 512, 0, stream>>>(aggb, xb, WT1l, WT1r, bb[0], h1, M, 1536, 768, 1, Mt, 6);

  // L2: GEMM C2 = h1 @ [Wl2|Wr2]  (N x 1536), fused sliced agg over 768 -> h2
  gs_gemm<<<Mt * 6, 512, 0, stream>>>(h1, nullptr, WT2, nullptr, nullptr, C2, M, 1536, 1536, 0, Mt, 6);
  gs_agg_slice<<<dim3(N, 6), 64, 0, stream>>>(C2, 1536, 768, rp, col, bb[1], h2, nullptr, 768, 1);

  // L3: GEMM C3 = h2 @ [Wl3|Wr3]  (N x 768), fused sliced agg over 384 -> h3
  gs_gemm<<<Mt * 3, 512, 0, stream>>>(h2, nullptr, WT3, nullptr, nullptr, C3, M, 768, 768, 0, Mt, 3);
  gs_agg_slice<<<dim3(N, 3), 64, 0, stream>>>(C3, 768, 384, rp, col, bb[2], h3, nullptr, 384, 1);

  // L4: GEMM C4 = h3 @ [Wl4|Wr4]  (N x 512), fused sliced agg over 256 -> h4 (bf16) + d_out (fp32)
  gs_gemm<<<Mt * 2, 512, 0, stream>>>(h3, nullptr, WT4, nullptr, nullptr, C4, M, 512, 384, 0, Mt, 2);
  gs_agg_slice<<<dim3(N, 2), 64, 0, stream>>>(C4, 512, 256, rp, col, bb[3], h4, houtF, 256, 1);

  // L5: per-node dot -> yz5 [N,10] fp32, then tiny agg over 5 -> out
  gs_l5dot<<<N, 64, 0, stream>>>(h4, Wl[4], Wr[4], yz5);
  gs_l5agg<<<N, 64, 0, stream>>>(yz5, rp, col, bb[4], out5);
}

// Round 4
// 661.907 us; speedup vs baseline: 1.1109x; 1.0287x over previous
//
#include <hip/hip_runtime.h>
#include <stdint.h>

typedef __attribute__((ext_vector_type(8))) short short8;
typedef __attribute__((ext_vector_type(4))) float f32x4;

__device__ __forceinline__ float bf2f(unsigned short s) {
  return __uint_as_float(((unsigned)s) << 16);
}
__device__ __forceinline__ unsigned short f2bf(float f) {
  unsigned u = __float_as_uint(f);
  u += 0x7fffu + ((u >> 16) & 1u);   // round-to-nearest-even
  return (unsigned short)(u >> 16);
}

// ---------------- CSR build ----------------
__global__ void gs_count_deg(const int* __restrict__ dst, int* __restrict__ cnt, int E) {
  int e = blockIdx.x * 256 + threadIdx.x;
  if (e < E) atomicAdd(&cnt[dst[e]], 1);
}

// 3-phase scan: A) per-1024-chunk local exclusive scan + chunk sum
__global__ void gs_scanA(const int* __restrict__ cnt, int* __restrict__ rp,
                         int* __restrict__ bsum, int n) {
  __shared__ int sm[256];
  const int b = blockIdx.x, t = threadIdx.x;
  const int base = b * 1024 + t * 4;
  int v[4]; int s = 0;
#pragma unroll
  for (int i = 0; i < 4; ++i) { v[i] = (base + i < n) ? cnt[base + i] : 0; s += v[i]; }
  sm[t] = s;
  __syncthreads();
  for (int off = 1; off < 256; off <<= 1) {
    int x = (t >= off) ? sm[t - off] : 0;
    __syncthreads();
    sm[t] += x;
    __syncthreads();
  }
  int run = sm[t] - s;
#pragma unroll
  for (int i = 0; i < 4; ++i) { if (base + i < n) rp[base + i] = run; run += v[i]; }
  if (t == 255) bsum[b] = sm[255];
}

// C) add chunk offsets (bsum scanned inline by wave 0 — replaces old scanB
//    kernel; requires nbChunks <= 64, i.e. N <= 65536), replicate into cur,
//    set rp[n].
__global__ void gs_scanC(int* __restrict__ rp, int* __restrict__ cur,
                         const int* __restrict__ bsum, int n, int nb) {
  __shared__ int sOff[65];   // sOff[k] = exclusive prefix of bsum; sOff[64]=total
  const int t = threadIdx.x;
  if (t < 64) {              // wave 0 only
    int bv = (t < nb) ? bsum[t] : 0;
    int run = bv;
#pragma unroll
    for (int off = 1; off < 64; off <<= 1) {
      int x = __shfl_up(run, off, 64);
      if (t >= off) run += x;
    }
    sOff[t] = run - bv;                     // exclusive prefix
    if (t == 63) sOff[64] = run;            // grand total
  }
  __syncthreads();
  int i = blockIdx.x * 256 + threadIdx.x;
  if (i < n) {
    int v = rp[i] + sOff[i >> 10];
    rp[i] = v;
    cur[i] = v;
  }
  if (i == n) rp[n] = sOff[64];
}

__global__ void gs_fill_csr(const int* __restrict__ src, const int* __restrict__ dst,
                            int* __restrict__ cur, int* __restrict__ col, int E) {
  int e = blockIdx.x * 256 + threadIdx.x;
  if (e < E) {
    int pos = atomicAdd(&cur[dst[e]], 1);
    col[pos] = src[e];
  }
}

// ---------------- conversions / weight packing ----------------
__global__ void gs_f32_to_bf16(const float* __restrict__ in, unsigned short* __restrict__ out, int n4) {
  int i = blockIdx.x * 256 + threadIdx.x;
  if (i < n4) {
    float4 f = ((const float4*)in)[i];
    ushort4 o;
    o.x = f2bf(f.x); o.y = f2bf(f.y); o.z = f2bf(f.z); o.w = f2bf(f.w);
    ((ushort4*)out)[i] = o;
  }
}

// batched tiled transpose-pack: W [K x F] fp32 row-major -> WT [F x K] bf16 row-major
struct TP { const float* W; unsigned short* WT; int K, F; };
struct TP8 { TP t[8]; };

__global__ void gs_tpack8(TP8 args) {
  const TP a = args.t[blockIdx.z];
  const int k0 = blockIdx.x * 32, f0 = blockIdx.y * 32;
  if (k0 >= a.K || f0 >= a.F) return;
  __shared__ float t[32][33];
  const int tx = threadIdx.x, ty = threadIdx.y;
#pragma unroll
  for (int r = ty; r < 32; r += 8) {
    int k = k0 + r, f = f0 + tx;
    t[r][tx] = (k < a.K && f < a.F) ? a.W[(size_t)k * a.F + f] : 0.f;
  }
  __syncthreads();
#pragma unroll
  for (int r = ty; r < 32; r += 8) {
    int f = f0 + r, k = k0 + tx;
    if (f < a.F && k < a.K) a.WT[(size_t)f * a.K + k] = f2bf(t[tx][r]);
  }
}

// ---------------- sliced fused aggregation ----------------
// block = (node v, 128-col slice). 64 threads, ushort2/lane (256 B row footprint).
// Slice-major dispatch keeps the co-resident gather footprint ~N*256B (~5 MB)
// so the deg/8 per-XCD reuse lands in L2 instead of L3.
// R4: neighbor indices broadcast via __shfl (in-register) instead of LDS
// staging — removes 2 __syncthreads per 64-edge chunk and all __shared__ use.
// o = mean_{nb} C[nb, c0:c0+128] (+ C[v, zoff+c0 ...] if zoff>=0) (+bias) (relu?)
__global__ __launch_bounds__(64)
void gs_agg_slice(const unsigned short* __restrict__ C, int ldc, int zoff,
                  const int* __restrict__ rp, const int* __restrict__ col,
                  const float* __restrict__ bias,
                  unsigned short* __restrict__ hout, float* __restrict__ fout,
                  int F, int relu) {
  const int v = blockIdx.x;
  const int cc = blockIdx.y * 128 + 2 * threadIdx.x;
  const int l = threadIdx.x;
  const int s0 = rp[v], s1 = rp[v + 1];
  const float inv = 1.0f / (float)max(s1 - s0, 1);
  float a0 = 0.f, a1 = 0.f;
  for (int base = s0; base < s1; base += 64) {
    int m = min(s1 - base, 64);
    int myNb = (l < m) ? col[base + l] : 0;   // coalesced; lanes >= m unused
    int j = 0;
    for (; j + 4 <= m; j += 4) {
      int n0 = __shfl(myNb, j, 64);
      int n1 = __shfl(myNb, j + 1, 64);
      int n2 = __shfl(myNb, j + 2, 64);
      int n3 = __shfl(myNb, j + 3, 64);
      ushort2 u0 = *(const ushort2*)(C + (size_t)n0 * ldc + cc);
      ushort2 u1 = *(const ushort2*)(C + (size_t)n1 * ldc + cc);
      ushort2 u2 = *(const ushort2*)(C + (size_t)n2 * ldc + cc);
      ushort2 u3 = *(const ushort2*)(C + (size_t)n3 * ldc + cc);
      a0 += bf2f(u0.x) + bf2f(u1.x) + bf2f(u2.x) + bf2f(u3.x);
      a1 += bf2f(u0.y) + bf2f(u1.y) + bf2f(u2.y) + bf2f(u3.y);
    }
    for (; j < m; ++j) {
      int nj = __shfl(myNb, j, 64);
      ushort2 u = *(const ushort2*)(C + (size_t)nj * ldc + cc);
      a0 += bf2f(u.x); a1 += bf2f(u.y);
    }
  }
  float o0 = a0 * inv, o1 = a1 * inv;
  if (zoff >= 0) {
    ushort2 u = *(const ushort2*)(C + (size_t)v * ldc + zoff + cc);
    o0 += bf2f(u.x); o1 += bf2f(u.y);
  }
  if (bias) { o0 += bias[cc]; o1 += bias[cc + 1]; }
  if (relu) { o0 = fmaxf(o0, 0.f); o1 = fmaxf(o1, 0.f); }
  if (hout) {
    ushort2 u; u.x = f2bf(o0); u.y = f2bf(o1);
    *(ushort2*)(hout + (size_t)v * F + cc) = u;
  }
  if (fout) *(float2*)(fout + (size_t)v * F + cc) = make_float2(o0, o1);
}

// ---------------- GEMM: C = act(A1@B1^T [+ A2@B2^T] + bias) ----------------
// 256x256 tile, BK=64, 8 waves (2M x 4N), 512 threads. 8-phase counted-vmcnt
// schedule with register-resident fragments (24 b128 reads/wave/K-tile) and
// ONE barrier per phase. Phase = {reads | STAGE | setprio(1) MFMA setprio(0)
// | [vmcnt(4) at ph4/ph8] | s_barrier(asm, memory clobber)}.
// Safety: every ds_read's consuming MFMA is in-phase (reads drained before
// the wave's phase-end barrier); every stage-target region's last reader
// drained >=1 barrier before the GLL issues; vmcnt(4) at ph4/ph8 certifies
// the next K-tile fully resident. STAGE addresses hoisted.
// LDS 128 KiB: 2 dbuf x 2 halves x [128x64] x {A,B}; halves by quadrant-of-use
// (A: row bit6; B: col bit5). XOR swizzle (chunk ^= row&7) on pre-swizzled
// GLOBAL source + ds_read addr (both-sides involution, rule #21). Tail stages
// clamp source (dead data) so the vmcnt window is identical every iteration.
// Requires Nn%256==0, K%128==0. M arbitrary (row clamp; OOB rows not stored).
#define GLL(SRC, DST) __builtin_amdgcn_global_load_lds(                        \
    (const __attribute__((address_space(1))) unsigned int*)(SRC),              \
    (__attribute__((address_space(3))) unsigned int*)(DST), 16, 0, 0)

#define PHASE(T, MH, NH, RD_A, RD_B, ST_T, ST_B, ST_H, DO_VM)                  \
  {                                                                            \
    const int buf_ = (T) & 1;                                                  \
    if (RD_A) {                                                                \
      const unsigned short* Ab_ = &lA[buf_][MH][0];                            \
      _Pragma("unroll")                                                        \
      for (int fi = 0; fi < 4; ++fi) {                                         \
        int lra = wMl + fi * 16;                                               \
        _Pragma("unroll")                                                      \
        for (int ks = 0; ks < 2; ++ks) {                                       \
          int ch = (ks * 4 + qk) ^ (lra & 7);                                  \
          rA[fi][ks] = *(const short8*)&Ab_[lra * 64 + ch * 8];                \
        }                                                                      \
      }                                                                        \
    }                                                                          \
    if (RD_B) {                                                                \
      const unsigned short* Bb_ = &lB[buf_][NH][0];                            \
      _Pragma("unroll")                                                        \
      for (int fj = 0; fj < 2; ++fj) {                                         \
        int lrb = wNl + fj * 16;                                               \
        _Pragma("unroll")                                                      \
        for (int ks = 0; ks < 2; ++ks) {                                       \
          int ch = (ks * 4 + qk) ^ (lrb & 7);                                  \
          rB[NH][fj][ks] = *(const short8*)&Bb_[lrb * 64 + ch * 8];            \
        }                                                                      \
      }                                                                        \
    }                                                                          \
    STAGE(ST_T, ST_B, ST_H);                                                   \
    __builtin_amdgcn_s_setprio(1);                                             \
    _Pragma("unroll")                                                          \
    for (int fi = 0; fi < 4; ++fi)                                             \
      _Pragma("unroll")                                                        \
      for (int fj = 0; fj < 2; ++fj)                                           \
        _Pragma("unroll")                                                      \
        for (int ks = 0; ks < 2; ++ks)                                         \
          acc[MH][fi][NH][fj] = __builtin_amdgcn_mfma_f32_16x16x32_bf16(       \
              rA[fi][ks], rB[NH][fj][ks], acc[MH][fi][NH][fj], 0, 0, 0);       \
    __builtin_amdgcn_s_setprio(0);                                             \
    if (DO_VM) asm volatile("s_waitcnt vmcnt(4)" ::: "memory");                \
    asm volatile("s_barrier" ::: "memory");                                    \
  }

__global__ __launch_bounds__(512, 2)
void gs_gemm(const unsigned short* __restrict__ A1, const unsigned short* __restrict__ A2,
             const unsigned short* __restrict__ B1, const unsigned short* __restrict__ B2,
             const float* __restrict__ bias, unsigned short* __restrict__ Hout,
             int M, int Nn, int K, int doRelu, int Mt, int Nt) {
  __shared__ unsigned short lA[2][2][8192];   // [buf][half][128*64]
  __shared__ unsigned short lB[2][2][8192];
  const int tid = threadIdx.x;
  const int wid = tid >> 6;
  const int lane = tid & 63;

  // 1-D grid swizzled: groups of MG M-tiles sweep all N-tiles (A stays L2-hot)
  const int MG = 8;
  const int per = MG * Nt;
  const int g = blockIdx.x / per;
  const int rem = blockIdx.x - g * per;
  const int gsz = min(MG, Mt - g * MG);
  const int nIdx = rem / gsz;
  const int mIdx = g * MG + (rem - nIdx * gsz);
  const int bM = mIdx * 256;
  const int bN = nIdx * 256;

  const int wM_ = wid >> 2;                 // 0..1 (M half of tile)
  const int wN_ = wid & 3;                  // 0..3 (N quarter)
  const int qk  = lane >> 4;                // K-subchunk of fragment
  const int wMl = wM_ * 64 + (lane & 15);   // A local row base in half-region
  const int wNl = wN_ * 32 + (lane & 15);   // B local row base in half-region

  // staging geometry: thread covers chunks tid and 512+tid of a half-tile
  // (chunk = 16B; half-tile = [128 local rows][64 K] = 1024 chunks)
  const int lr  = tid >> 3;                                // local row, chunk1
  const int swk = ((tid & 7) ^ (lr & 7)) * 8;              // swizzled src K-chunk (ushorts)
  const int rB0 = (lr >> 5) * 64 + (lr & 31);              // B global-row part

  const int kt = K / 64;                    // K-tiles per pass
  const int nt = A2 ? 2 * kt : kt;          // total K-tiles (always even)
  const int NI = nt / 2;

  f32x4 acc[2][4][2][2];
#pragma unroll
  for (int a = 0; a < 2; ++a)
#pragma unroll
    for (int b = 0; b < 4; ++b)
#pragma unroll
      for (int c = 0; c < 2; ++c)
#pragma unroll
        for (int d = 0; d < 2; ++d) acc[a][b][c][d] = (f32x4){0.f, 0.f, 0.f, 0.f};

  // register-resident fragments (static indexing only — rule #20)
  short8 rA[4][2];        // A frags of current M-half
  short8 rB[2][2][2];     // B frags of both N-halves [nh][fj][ks]

  // hoisted per-thread staging offsets (elements): row*K + swizzled chunk
  size_t offA[2][2], offB[2][2];
#pragma unroll
  for (int h = 0; h < 2; ++h) {
    int r1u = bM + h * 64 + lr;
    int r1 = (r1u < M) ? r1u : (M - 1);
    int r2u = r1u + 128;
    int r2 = (r2u < M) ? r2u : (M - 1);
    offA[h][0] = (size_t)r1 * K + swk;
    offA[h][1] = (size_t)r2 * K + swk;
    int rb = bN + h * 32 + rB0;
    offB[h][0] = (size_t)rb * K + swk;
    offB[h][1] = (size_t)(rb + 128) * K + swk;
  }

  auto STAGE = [&](int t, int isB, int h) {
    const int tc = (t < nt) ? t : (nt - 1);    // clamped source (tail: dead data)
    const int pass = (tc >= kt) ? 1 : 0;
    const int k0 = (tc - pass * kt) * 64;      // wave-uniform
    const int buf = t & 1;
    if (!isB) {
      const unsigned short* Ap = (pass ? A2 : A1) + k0;
      char* d = (char*)&lA[buf][h][0] + wid * 1024;
      GLL(Ap + offA[h][0], d);
      GLL(Ap + offA[h][1], d + 8192);
    } else {
      const unsigned short* Bp = (pass ? B2 : B1) + k0;
      char* d = (char*)&lB[buf][h][0] + wid * 1024;
      GLL(Bp + offB[h][0], d);
      GLL(Bp + offB[h][1], d + 8192);
    }
  };

  // prologue: t0 complete + t1.{A0,B0}; wait t0 landed (last 2 half-tiles may fly)
  STAGE(0, 0, 0); STAGE(0, 1, 0); STAGE(0, 0, 1); STAGE(0, 1, 1);
  STAGE(1, 0, 0); STAGE(1, 1, 0);
  asm volatile("s_waitcnt vmcnt(4)" ::: "memory");
  asm volatile("s_barrier" ::: "memory");

  for (int i = 0; i < NI; ++i) {
    const int t0 = 2 * i, t1 = t0 + 1, t2 = t0 + 2, t3 = t0 + 3;
    PHASE(t0, 0, 0, 1, 1, t1, 0, 1, 0)   // rd A0+B0; stage t1.A1 (dead region)
    PHASE(t0, 0, 1, 0, 1, t1, 1, 1, 0)   // rd B1;    stage t1.B1
    PHASE(t0, 1, 0, 1, 0, t2, 0, 0, 0)   // rd A1;    stage t2.A0 (dead after ph1)
    PHASE(t0, 1, 1, 0, 0, t2, 1, 0, 1)   // pure MFMA; stage t2.B0; vmcnt(4): t1 landed
    PHASE(t1, 0, 0, 1, 1, t2, 0, 1, 0)
    PHASE(t1, 0, 1, 0, 1, t2, 1, 1, 0)
    PHASE(t1, 1, 0, 1, 0, t3, 0, 0, 0)
    PHASE(t1, 1, 1, 0, 0, t3, 1, 0, 1)   // vmcnt(4): t2 landed
  }

  // C/D layout: col = lane&15, row = (lane>>4)*4 + reg   [m89/m91]
#pragma unroll
  for (int mh = 0; mh < 2; ++mh)
#pragma unroll
    for (int fi = 0; fi < 4; ++fi) {
      const int row0 = bM + wM_ * 128 + mh * 64 + fi * 16 + (lane >> 4) * 4;
#pragma unroll
      for (int r = 0; r < 4; ++r) {
        const int row = row0 + r;
        if (row >= M) continue;
#pragma unroll
        for (int nh = 0; nh < 2; ++nh)
#pragma unroll
          for (int fj = 0; fj < 2; ++fj) {
            const int colN = bN + wN_ * 64 + nh * 32 + fj * 16 + (lane & 15);
            float v = acc[mh][fi][nh][fj][r];
            if (bias) v += bias[colN];
            if (doRelu) v = fmaxf(v, 0.f);
            Hout[(size_t)row * Nn + colN] = f2bf(v);
          }
      }
    }
}

// ---------------- layer 5 ----------------
// yz[v, 0:5] = h4[v]@Wl5, yz[v, 5:10] = h4[v]@Wr5   (fp32)
// R4: 4 nodes per 256-thread block (4 wave-aligned groups of 64) — weights
// loaded into LDS once per block instead of once per node (4x fewer blocks,
// 4x less redundant weight traffic).
__global__ __launch_bounds__(256)
void gs_l5dot(const unsigned short* __restrict__ h4, const float* __restrict__ Wl,
              const float* __restrict__ Wr, float* __restrict__ yz, int N) {
  __shared__ float sW[2560];
  const int t = threadIdx.x;
  for (int i = t; i < 2560; i += 256) sW[i] = (i < 1280) ? Wl[i] : Wr[i - 1280];
  __syncthreads();
  const int v = blockIdx.x * 4 + (t >> 6);
  if (v >= N) return;
  const int l = t & 63;
  ushort4 u = ((const ushort4*)(h4 + (size_t)v * 256))[l];   // k = 4l..4l+3
  float hv[4] = {bf2f(u.x), bf2f(u.y), bf2f(u.z), bf2f(u.w)};
  float acc[10];
#pragma unroll
  for (int n = 0; n < 10; ++n) acc[n] = 0.f;
#pragma unroll
  for (int tt = 0; tt < 4; ++tt) {
    int k = 4 * l + tt;
#pragma unroll
    for (int n = 0; n < 5; ++n) {
      acc[n] += hv[tt] * sW[k * 5 + n];
      acc[5 + n] += hv[tt] * sW[1280 + k * 5 + n];
    }
  }
#pragma unroll
  for (int n = 0; n < 10; ++n)
    for (int off = 32; off > 0; off >>= 1) acc[n] += __shfl_down(acc[n], off, 64);
  if (l == 0) {
#pragma unroll
    for (int n = 0; n < 10; ++n) yz[(size_t)v * 10 + n] = acc[n];
  }
}

// out[v] = mean_{nb} y5[nb] + z5[v] + b  (no relu)
__global__ __launch_bounds__(64)
void gs_l5agg(const float* __restrict__ yz, const int* __restrict__ rp,
              const int* __restrict__ col, const float* __restrict__ b,
              float* __restrict__ out) {
  const int v = blockIdx.x;
  const int l = threadIdx.x;
  const int s0 = rp[v], s1 = rp[v + 1];
  const float inv = 1.0f / (float)max(s1 - s0, 1);
  float acc[5] = {0.f, 0.f, 0.f, 0.f, 0.f};
  for (int e = s0 + l; e < s1; e += 64) {
    const float* yr = yz + (size_t)col[e] * 10;
#pragma unroll
    for (int n = 0; n < 5; ++n) acc[n] += yr[n];
  }
#pragma unroll
  for (int n = 0; n < 5; ++n)
    for (int off = 32; off > 0; off >>= 1) acc[n] += __shfl_down(acc[n], off, 64);
  if (l == 0) {
#pragma unroll
    for (int n = 0; n < 5; ++n)
      out[(size_t)v * 5 + n] = acc[n] * inv + yz[(size_t)v * 10 + 5 + n] + b[n];
  }
}

// ---------------- launcher ----------------
extern "C" void kernel_launch(void* const* d_in, const int* in_sizes, int n_in,
                              void* d_out, int out_size, void* d_ws, size_t ws_size,
                              hipStream_t stream) {
  const float* x = (const float*)d_in[0];
  const int* ei = (const int*)d_in[1];
  const int N = in_sizes[0] / 768;
  const int E = in_sizes[1] / 2;
  const int* src = ei;
  const int* dst = ei + E;

  const float* Wl[5];
  const float* Wr[5];
  const float* bb[5];
  for (int l = 0; l < 5; ++l) {
    Wl[l] = (const float*)d_in[2 + 3 * l];
    Wr[l] = (const float*)d_in[3 + 3 * l];
    bb[l] = (const float*)d_in[4 + 3 * l];
  }

  char* w = (char*)d_ws;
  size_t off = 0;
  auto take = [&](size_t bytes) -> char* {
    char* p = w + off;
    off = (off + bytes + 255) & ~(size_t)255;
    return p;
  };
  // arenas (aliased over layer lifetime)
  unsigned short* ar1 = (unsigned short*)take((size_t)N * 768 * 2);   // xb -> C3
  unsigned short* ar2 = (unsigned short*)take((size_t)N * 768 * 2);   // aggb -> h2
  unsigned short* ar3 = (unsigned short*)take((size_t)N * 1536 * 2);  // h1 -> C4|h3|h4|yz5
  unsigned short* C2  = (unsigned short*)take((size_t)N * 1536 * 2);
  int* cnt  = (int*)take((size_t)N * 4);
  int* rp   = (int*)take((size_t)(N + 1) * 4);
  int* cur  = (int*)take((size_t)N * 4);
  int* col  = (int*)take((size_t)E * 4);
  const int nbChunks = (N + 1023) / 1024;
  int* bsum = (int*)take((size_t)(nbChunks + 1) * 4);
  unsigned short* WT1l = (unsigned short*)take((size_t)1536 * 768 * 2);
  unsigned short* WT1r = (unsigned short*)take((size_t)1536 * 768 * 2);
  unsigned short* WT2  = (unsigned short*)take((size_t)1536 * 1536 * 2);
  unsigned short* WT3  = (unsigned short*)take((size_t)768 * 768 * 2);
  unsigned short* WT4  = (unsigned short*)take((size_t)512 * 384 * 2);

  unsigned short* xb   = ar1;
  unsigned short* C3   = ar1;
  unsigned short* aggb = ar2;
  unsigned short* h2   = ar2;
  unsigned short* h1   = ar3;
  unsigned short* C4   = ar3;                                  // N x 512
  unsigned short* h3   = ar3 + (size_t)N * 512;                // N x 384
  unsigned short* h4   = ar3 + (size_t)N * (512 + 384);        // N x 256
  float*          yz5  = (float*)(ar3 + (size_t)N * (512 + 384 + 256)); // N x 10 f32

  const int M = N;
  const int Mt = (M + 255) / 256;          // 256-row tiles for the 8-phase GEMM

  // CSR build (scanB folded into scanC: wave-0 shuffle scan, nbChunks <= 64)
  hipMemsetAsync(cnt, 0, (size_t)N * 4, stream);
  gs_count_deg<<<(E + 255) / 256, 256, 0, stream>>>(dst, cnt, E);
  gs_scanA<<<nbChunks, 256, 0, stream>>>(cnt, rp, bsum, N);
  gs_scanC<<<(N + 256) / 256, 256, 0, stream>>>(rp, cur, bsum, N, nbChunks);
  gs_fill_csr<<<(E + 255) / 256, 256, 0, stream>>>(src, dst, cur, col, E);

  // conversions (all coalesced); batched transpose-pack (1 launch)
  gs_f32_to_bf16<<<((N * 768 / 4) + 255) / 256, 256, 0, stream>>>(x, xb, N * 768 / 4);
  TP8 tp;
  tp.t[0] = {Wl[0], WT1l, 768, 1536};
  tp.t[1] = {Wr[0], WT1r, 768, 1536};
  tp.t[2] = {Wl[1], WT2, 1536, 768};
  tp.t[3] = {Wr[1], WT2 + (size_t)768 * 1536, 1536, 768};
  tp.t[4] = {Wl[2], WT3, 768, 384};
  tp.t[5] = {Wr[2], WT3 + (size_t)384 * 768, 768, 384};
  tp.t[6] = {Wl[3], WT4, 384, 256};
  tp.t[7] = {Wr[3], WT4 + (size_t)256 * 384, 384, 256};
  gs_tpack8<<<dim3(48, 48, 8), dim3(32, 8), 0, stream>>>(tp);

  float* houtF = (float*)d_out;                 // [N,256] fp32
  float* out5  = (float*)d_out + (size_t)N * 256;

  // L1: agg-before (Fin 768 < Fout 1536), dual GEMM -> h1 (relu+bias)
  gs_agg_slice<<<dim3(N, 6), 64, 0, stream>>>(xb, 768, -1, rp, col, nullptr, aggb, nullptr, 768, 0);
  gs_gemm<<<Mt * 6, 512, 0, stream>>>(aggb, xb, WT1l, WT1r, bb[0], h1, M, 1536, 768, 1, Mt, 6);

  // L2: GEMM C2 = h1 @ [Wl2|Wr2]  (N x 1536), fused sliced agg over 768 -> h2
  gs_gemm<<<Mt * 6, 512, 0, stream>>>(h1, nullptr, WT2, nullptr, nullptr, C2, M, 1536, 1536, 0, Mt, 6);
  gs_agg_slice<<<dim3(N, 6), 64, 0, stream>>>(C2, 1536, 768, rp, col, bb[1], h2, nullptr, 768, 1);

  // L3: GEMM C3 = h2 @ [Wl3|Wr3]  (N x 768), fused sliced agg over 384 -> h3
  gs_gemm<<<Mt * 3, 512, 0, stream>>>(h2, nullptr, WT3, nullptr, nullptr, C3, M, 768, 768, 0, Mt, 3);
  gs_agg_slice<<<dim3(N, 3), 64, 0, stream>>>(C3, 768, 384, rp, col, bb[2], h3, nullptr, 384, 1);

  // L4: GEMM C4 = h3 @ [Wl4|Wr4]  (N x 512), fused sliced agg over 256 -> h4 (bf16) + d_out (fp32)
  gs_gemm<<<Mt * 2, 512, 0, stream>>>(h3, nullptr, WT4, nullptr, nullptr, C4, M, 512, 384, 0, Mt, 2);
  gs_agg_slice<<<dim3(N, 2), 64, 0, stream>>>(C4, 512, 256, rp, col, bb[3], h4, houtF, 256, 1);

  // L5: per-node dot -> yz5 [N,10] fp32 (4 nodes/block), tiny agg over 5 -> out
  gs_l5dot<<<(N + 3) / 4, 256, 0, stream>>>(h4, Wl[4], Wr[4], yz5, N);
  gs_l5agg<<<N, 64, 0, stream>>>(yz5, rp, col, bb[4], out5);
}

// Round 5
// 653.429 us; speedup vs baseline: 1.1253x; 1.0130x over previous
//
#include <hip/hip_runtime.h>
#include <stdint.h>

typedef __attribute__((ext_vector_type(8))) short short8;
typedef __attribute__((ext_vector_type(4))) float f32x4;

__device__ __forceinline__ float bf2f(unsigned short s) {
  return __uint_as_float(((unsigned)s) << 16);
}
__device__ __forceinline__ unsigned short f2bf(float f) {
  unsigned u = __float_as_uint(f);
  u += 0x7fffu + ((u >> 16) & 1u);   // round-to-nearest-even
  return (unsigned short)(u >> 16);
}

// ---------------- CSR build ----------------
__global__ void gs_count_deg(const int* __restrict__ dst, int* __restrict__ cnt, int E) {
  int e = blockIdx.x * 256 + threadIdx.x;
  if (e < E) atomicAdd(&cnt[dst[e]], 1);
}

// 3-phase scan: A) per-1024-chunk local exclusive scan + chunk sum
__global__ void gs_scanA(const int* __restrict__ cnt, int* __restrict__ rp,
                         int* __restrict__ bsum, int n) {
  __shared__ int sm[256];
  const int b = blockIdx.x, t = threadIdx.x;
  const int base = b * 1024 + t * 4;
  int v[4]; int s = 0;
#pragma unroll
  for (int i = 0; i < 4; ++i) { v[i] = (base + i < n) ? cnt[base + i] : 0; s += v[i]; }
  sm[t] = s;
  __syncthreads();
  for (int off = 1; off < 256; off <<= 1) {
    int x = (t >= off) ? sm[t - off] : 0;
    __syncthreads();
    sm[t] += x;
    __syncthreads();
  }
  int run = sm[t] - s;
#pragma unroll
  for (int i = 0; i < 4; ++i) { if (base + i < n) rp[base + i] = run; run += v[i]; }
  if (t == 255) bsum[b] = sm[255];
}

// C) add chunk offsets (bsum scanned inline by wave 0; nbChunks <= 64),
//    replicate into cur, set rp[n].
__global__ void gs_scanC(int* __restrict__ rp, int* __restrict__ cur,
                         const int* __restrict__ bsum, int n, int nb) {
  __shared__ int sOff[65];
  const int t = threadIdx.x;
  if (t < 64) {
    int bv = (t < nb) ? bsum[t] : 0;
    int run = bv;
#pragma unroll
    for (int off = 1; off < 64; off <<= 1) {
      int x = __shfl_up(run, off, 64);
      if (t >= off) run += x;
    }
    sOff[t] = run - bv;
    if (t == 63) sOff[64] = run;
  }
  __syncthreads();
  int i = blockIdx.x * 256 + threadIdx.x;
  if (i < n) {
    int v = rp[i] + sOff[i >> 10];
    rp[i] = v;
    cur[i] = v;
  }
  if (i == n) rp[n] = sOff[64];
}

__global__ void gs_fill_csr(const int* __restrict__ src, const int* __restrict__ dst,
                            int* __restrict__ cur, int* __restrict__ col, int E) {
  int e = blockIdx.x * 256 + threadIdx.x;
  if (e < E) {
    int pos = atomicAdd(&cur[dst[e]], 1);
    col[pos] = src[e];
  }
}

// ---------------- conversions / weight packing ----------------
__global__ void gs_f32_to_bf16(const float* __restrict__ in, unsigned short* __restrict__ out, int n4) {
  int i = blockIdx.x * 256 + threadIdx.x;
  if (i < n4) {
    float4 f = ((const float4*)in)[i];
    ushort4 o;
    o.x = f2bf(f.x); o.y = f2bf(f.y); o.z = f2bf(f.z); o.w = f2bf(f.w);
    ((ushort4*)out)[i] = o;
  }
}

// batched tiled transpose-pack: W [K x F] fp32 row-major -> WT [F x K] bf16 row-major
struct TP { const float* W; unsigned short* WT; int K, F; };
struct TP8 { TP t[8]; };

__global__ void gs_tpack8(TP8 args) {
  const TP a = args.t[blockIdx.z];
  const int k0 = blockIdx.x * 32, f0 = blockIdx.y * 32;
  if (k0 >= a.K || f0 >= a.F) return;
  __shared__ float t[32][33];
  const int tx = threadIdx.x, ty = threadIdx.y;
#pragma unroll
  for (int r = ty; r < 32; r += 8) {
    int k = k0 + r, f = f0 + tx;
    t[r][tx] = (k < a.K && f < a.F) ? a.W[(size_t)k * a.F + f] : 0.f;
  }
  __syncthreads();
#pragma unroll
  for (int r = ty; r < 32; r += 8) {
    int f = f0 + r, k = k0 + tx;
    if (f < a.F && k < a.K) a.WT[(size_t)f * a.K + k] = f2bf(t[tx][r]);
  }
}

// ---------------- sliced fused aggregation ----------------
// block = (node v, slice of VW*64 cols). 64 threads, VW ushorts/lane.
// VW=4 -> 8B/lane (coalescing sweet spot, 512B/row-request); VW=2 -> 4B/lane
// for F not divisible by 256. Neighbor indices broadcast via __shfl.
// o = mean_{nb} C[nb, cc..] (+ C[v, zoff+cc..] if zoff>=0) (+bias) (relu?)
template<int VW>
__global__ __launch_bounds__(64)
void gs_agg_sliceT(const unsigned short* __restrict__ C, int ldc, int zoff,
                   const int* __restrict__ rp, const int* __restrict__ col,
                   const float* __restrict__ bias,
                   unsigned short* __restrict__ hout, float* __restrict__ fout,
                   int F, int relu) {
  const int v = blockIdx.x;
  const int l = threadIdx.x;
  const int cc = blockIdx.y * (64 * VW) + VW * l;
  const int s0 = rp[v], s1 = rp[v + 1];
  const float inv = 1.0f / (float)max(s1 - s0, 1);
  float a[VW];
#pragma unroll
  for (int q = 0; q < VW; ++q) a[q] = 0.f;

  auto accum = [&](int nrow) {
    const unsigned short* p = C + (size_t)nrow * ldc + cc;
    if constexpr (VW == 4) {
      ushort4 u = *(const ushort4*)p;
      a[0] += bf2f(u.x); a[1] += bf2f(u.y); a[2] += bf2f(u.z); a[3] += bf2f(u.w);
    } else {
      ushort2 u = *(const ushort2*)p;
      a[0] += bf2f(u.x); a[1] += bf2f(u.y);
    }
  };

  for (int base = s0; base < s1; base += 64) {
    int m = min(s1 - base, 64);
    int myNb = (l < m) ? col[base + l] : 0;
    int j = 0;
    for (; j + 4 <= m; j += 4) {
      int n0 = __shfl(myNb, j, 64);
      int n1 = __shfl(myNb, j + 1, 64);
      int n2 = __shfl(myNb, j + 2, 64);
      int n3 = __shfl(myNb, j + 3, 64);
      accum(n0); accum(n1); accum(n2); accum(n3);
    }
    for (; j < m; ++j) accum(__shfl(myNb, j, 64));
  }

  float o[VW];
#pragma unroll
  for (int q = 0; q < VW; ++q) o[q] = a[q] * inv;
  if (zoff >= 0) {
    const unsigned short* p = C + (size_t)v * ldc + zoff + cc;
    if constexpr (VW == 4) {
      ushort4 u = *(const ushort4*)p;
      o[0] += bf2f(u.x); o[1] += bf2f(u.y); o[2] += bf2f(u.z); o[3] += bf2f(u.w);
    } else {
      ushort2 u = *(const ushort2*)p;
      o[0] += bf2f(u.x); o[1] += bf2f(u.y);
    }
  }
  if (bias) {
#pragma unroll
    for (int q = 0; q < VW; ++q) o[q] += bias[cc + q];
  }
  if (relu) {
#pragma unroll
    for (int q = 0; q < VW; ++q) o[q] = fmaxf(o[q], 0.f);
  }
  if (hout) {
    if constexpr (VW == 4) {
      ushort4 u; u.x = f2bf(o[0]); u.y = f2bf(o[1]); u.z = f2bf(o[2]); u.w = f2bf(o[3]);
      *(ushort4*)(hout + (size_t)v * F + cc) = u;
    } else {
      ushort2 u; u.x = f2bf(o[0]); u.y = f2bf(o[1]);
      *(ushort2*)(hout + (size_t)v * F + cc) = u;
    }
  }
  if (fout) {
    if constexpr (VW == 4)
      *(float4*)(fout + (size_t)v * F + cc) = make_float4(o[0], o[1], o[2], o[3]);
    else
      *(float2*)(fout + (size_t)v * F + cc) = make_float2(o[0], o[1]);
  }
}

// ---------------- GEMM: C = act(A1@B1^T [+ A2@B2^T] + bias) ----------------
// 256x256 tile, BK=64, 8 waves (2M x 4N), 512 threads. 8-phase counted-vmcnt
// schedule with register-resident fragments (24 b128 reads/wave/K-tile) and
// ONE barrier per phase. Phase = {reads | STAGE | setprio(1) MFMA setprio(0)
// | [vmcnt(4) at ph4/ph8] | s_barrier(asm, memory clobber)}.
// Frozen since R3 (best measured: 127.4 us @ L1/L2, MfmaUtil 31).
#define GLL(SRC, DST) __builtin_amdgcn_global_load_lds(                        \
    (const __attribute__((address_space(1))) unsigned int*)(SRC),              \
    (__attribute__((address_space(3))) unsigned int*)(DST), 16, 0, 0)

#define PHASE(T, MH, NH, RD_A, RD_B, ST_T, ST_B, ST_H, DO_VM)                  \
  {                                                                            \
    const int buf_ = (T) & 1;                                                  \
    if (RD_A) {                                                                \
      const unsigned short* Ab_ = &lA[buf_][MH][0];                            \
      _Pragma("unroll")                                                        \
      for (int fi = 0; fi < 4; ++fi) {                                         \
        int lra = wMl + fi * 16;                                               \
        _Pragma("unroll")                                                      \
        for (int ks = 0; ks < 2; ++ks) {                                       \
          int ch = (ks * 4 + qk) ^ (lra & 7);                                  \
          rA[fi][ks] = *(const short8*)&Ab_[lra * 64 + ch * 8];                \
        }                                                                      \
      }                                                                        \
    }                                                                          \
    if (RD_B) {                                                                \
      const unsigned short* Bb_ = &lB[buf_][NH][0];                            \
      _Pragma("unroll")                                                        \
      for (int fj = 0; fj < 2; ++fj) {                                         \
        int lrb = wNl + fj * 16;                                               \
        _Pragma("unroll")                                                      \
        for (int ks = 0; ks < 2; ++ks) {                                       \
          int ch = (ks * 4 + qk) ^ (lrb & 7);                                  \
          rB[NH][fj][ks] = *(const short8*)&Bb_[lrb * 64 + ch * 8];            \
        }                                                                      \
      }                                                                        \
    }                                                                          \
    STAGE(ST_T, ST_B, ST_H);                                                   \
    __builtin_amdgcn_s_setprio(1);                                             \
    _Pragma("unroll")                                                          \
    for (int fi = 0; fi < 4; ++fi)                                             \
      _Pragma("unroll")                                                        \
      for (int fj = 0; fj < 2; ++fj)                                           \
        _Pragma("unroll")                                                      \
        for (int ks = 0; ks < 2; ++ks)                                         \
          acc[MH][fi][NH][fj] = __builtin_amdgcn_mfma_f32_16x16x32_bf16(       \
              rA[fi][ks], rB[NH][fj][ks], acc[MH][fi][NH][fj], 0, 0, 0);       \
    __builtin_amdgcn_s_setprio(0);                                             \
    if (DO_VM) asm volatile("s_waitcnt vmcnt(4)" ::: "memory");                \
    asm volatile("s_barrier" ::: "memory");                                    \
  }

__global__ __launch_bounds__(512, 2)
void gs_gemm(const unsigned short* __restrict__ A1, const unsigned short* __restrict__ A2,
             const unsigned short* __restrict__ B1, const unsigned short* __restrict__ B2,
             const float* __restrict__ bias, unsigned short* __restrict__ Hout,
             int M, int Nn, int K, int doRelu, int Mt, int Nt) {
  __shared__ unsigned short lA[2][2][8192];   // [buf][half][128*64]
  __shared__ unsigned short lB[2][2][8192];
  const int tid = threadIdx.x;
  const int wid = tid >> 6;
  const int lane = tid & 63;

  // 1-D grid swizzled: groups of MG M-tiles sweep all N-tiles (A stays L2-hot)
  const int MG = 8;
  const int per = MG * Nt;
  const int g = blockIdx.x / per;
  const int rem = blockIdx.x - g * per;
  const int gsz = min(MG, Mt - g * MG);
  const int nIdx = rem / gsz;
  const int mIdx = g * MG + (rem - nIdx * gsz);
  const int bM = mIdx * 256;
  const int bN = nIdx * 256;

  const int wM_ = wid >> 2;                 // 0..1 (M half of tile)
  const int wN_ = wid & 3;                  // 0..3 (N quarter)
  const int qk  = lane >> 4;                // K-subchunk of fragment
  const int wMl = wM_ * 64 + (lane & 15);   // A local row base in half-region
  const int wNl = wN_ * 32 + (lane & 15);   // B local row base in half-region

  // staging geometry: thread covers chunks tid and 512+tid of a half-tile
  const int lr  = tid >> 3;                                // local row, chunk1
  const int swk = ((tid & 7) ^ (lr & 7)) * 8;              // swizzled src K-chunk
  const int rB0 = (lr >> 5) * 64 + (lr & 31);              // B global-row part

  const int kt = K / 64;                    // K-tiles per pass
  const int nt = A2 ? 2 * kt : kt;          // total K-tiles (always even)
  const int NI = nt / 2;

  f32x4 acc[2][4][2][2];
#pragma unroll
  for (int a = 0; a < 2; ++a)
#pragma unroll
    for (int b = 0; b < 4; ++b)
#pragma unroll
      for (int c = 0; c < 2; ++c)
#pragma unroll
        for (int d = 0; d < 2; ++d) acc[a][b][c][d] = (f32x4){0.f, 0.f, 0.f, 0.f};

  // register-resident fragments (static indexing only — rule #20)
  short8 rA[4][2];        // A frags of current M-half
  short8 rB[2][2][2];     // B frags of both N-halves [nh][fj][ks]

  // hoisted per-thread staging offsets (elements): row*K + swizzled chunk
  size_t offA[2][2], offB[2][2];
#pragma unroll
  for (int h = 0; h < 2; ++h) {
    int r1u = bM + h * 64 + lr;
    int r1 = (r1u < M) ? r1u : (M - 1);
    int r2u = r1u + 128;
    int r2 = (r2u < M) ? r2u : (M - 1);
    offA[h][0] = (size_t)r1 * K + swk;
    offA[h][1] = (size_t)r2 * K + swk;
    int rb = bN + h * 32 + rB0;
    offB[h][0] = (size_t)rb * K + swk;
    offB[h][1] = (size_t)(rb + 128) * K + swk;
  }

  auto STAGE = [&](int t, int isB, int h) {
    const int tc = (t < nt) ? t : (nt - 1);    // clamped source (tail: dead data)
    const int pass = (tc >= kt) ? 1 : 0;
    const int k0 = (tc - pass * kt) * 64;      // wave-uniform
    const int buf = t & 1;
    if (!isB) {
      const unsigned short* Ap = (pass ? A2 : A1) + k0;
      char* d = (char*)&lA[buf][h][0] + wid * 1024;
      GLL(Ap + offA[h][0], d);
      GLL(Ap + offA[h][1], d + 8192);
    } else {
      const unsigned short* Bp = (pass ? B2 : B1) + k0;
      char* d = (char*)&lB[buf][h][0] + wid * 1024;
      GLL(Bp + offB[h][0], d);
      GLL(Bp + offB[h][1], d + 8192);
    }
  };

  // prologue: t0 complete + t1.{A0,B0}; wait t0 landed
  STAGE(0, 0, 0); STAGE(0, 1, 0); STAGE(0, 0, 1); STAGE(0, 1, 1);
  STAGE(1, 0, 0); STAGE(1, 1, 0);
  asm volatile("s_waitcnt vmcnt(4)" ::: "memory");
  asm volatile("s_barrier" ::: "memory");

  for (int i = 0; i < NI; ++i) {
    const int t0 = 2 * i, t1 = t0 + 1, t2 = t0 + 2, t3 = t0 + 3;
    PHASE(t0, 0, 0, 1, 1, t1, 0, 1, 0)
    PHASE(t0, 0, 1, 0, 1, t1, 1, 1, 0)
    PHASE(t0, 1, 0, 1, 0, t2, 0, 0, 0)
    PHASE(t0, 1, 1, 0, 0, t2, 1, 0, 1)   // vmcnt(4): t1 landed
    PHASE(t1, 0, 0, 1, 1, t2, 0, 1, 0)
    PHASE(t1, 0, 1, 0, 1, t2, 1, 1, 0)
    PHASE(t1, 1, 0, 1, 0, t3, 0, 0, 0)
    PHASE(t1, 1, 1, 0, 0, t3, 1, 0, 1)   // vmcnt(4): t2 landed
  }

  // C/D layout: col = lane&15, row = (lane>>4)*4 + reg   [m89/m91]
#pragma unroll
  for (int mh = 0; mh < 2; ++mh)
#pragma unroll
    for (int fi = 0; fi < 4; ++fi) {
      const int row0 = bM + wM_ * 128 + mh * 64 + fi * 16 + (lane >> 4) * 4;
#pragma unroll
      for (int r = 0; r < 4; ++r) {
        const int row = row0 + r;
        if (row >= M) continue;
#pragma unroll
        for (int nh = 0; nh < 2; ++nh)
#pragma unroll
          for (int fj = 0; fj < 2; ++fj) {
            const int colN = bN + wN_ * 64 + nh * 32 + fj * 16 + (lane & 15);
            float v = acc[mh][fi][nh][fj][r];
            if (bias) v += bias[colN];
            if (doRelu) v = fmaxf(v, 0.f);
            Hout[(size_t)row * Nn + colN] = f2bf(v);
          }
      }
    }
}

// ---------------- layer 5 ----------------
// yz[v, 0:5] = h4[v]@Wl5, yz[v, 5:10] = h4[v]@Wr5   (fp32)
// 4 nodes per 256-thread block; weights in LDS once per block.
__global__ __launch_bounds__(256)
void gs_l5dot(const unsigned short* __restrict__ h4, const float* __restrict__ Wl,
              const float* __restrict__ Wr, float* __restrict__ yz, int N) {
  __shared__ float sW[2560];
  const int t = threadIdx.x;
  for (int i = t; i < 2560; i += 256) sW[i] = (i < 1280) ? Wl[i] : Wr[i - 1280];
  __syncthreads();
  const int v = blockIdx.x * 4 + (t >> 6);
  if (v >= N) return;
  const int l = t & 63;
  ushort4 u = ((const ushort4*)(h4 + (size_t)v * 256))[l];   // k = 4l..4l+3
  float hv[4] = {bf2f(u.x), bf2f(u.y), bf2f(u.z), bf2f(u.w)};
  float acc[10];
#pragma unroll
  for (int n = 0; n < 10; ++n) acc[n] = 0.f;
#pragma unroll
  for (int tt = 0; tt < 4; ++tt) {
    int k = 4 * l + tt;
#pragma unroll
    for (int n = 0; n < 5; ++n) {
      acc[n] += hv[tt] * sW[k * 5 + n];
      acc[5 + n] += hv[tt] * sW[1280 + k * 5 + n];
    }
  }
#pragma unroll
  for (int n = 0; n < 10; ++n)
    for (int off = 32; off > 0; off >>= 1) acc[n] += __shfl_down(acc[n], off, 64);
  if (l == 0) {
#pragma unroll
    for (int n = 0; n < 10; ++n) yz[(size_t)v * 10 + n] = acc[n];
  }
}

// out[v] = mean_{nb} y5[nb] + z5[v] + b  (no relu)
// R5: 16 lanes per node, 16 nodes per 256-thread block (deg~16 -> lanes busy).
__global__ __launch_bounds__(256)
void gs_l5agg(const float* __restrict__ yz, const int* __restrict__ rp,
              const int* __restrict__ col, const float* __restrict__ b,
              float* __restrict__ out, int N) {
  const int t = threadIdx.x;
  const int v = blockIdx.x * 16 + (t >> 4);
  if (v >= N) return;
  const int l = t & 15;
  const int s0 = rp[v], s1 = rp[v + 1];
  const float inv = 1.0f / (float)max(s1 - s0, 1);
  float acc[5] = {0.f, 0.f, 0.f, 0.f, 0.f};
  for (int e = s0 + l; e < s1; e += 16) {
    const float* yr = yz + (size_t)col[e] * 10;
#pragma unroll
    for (int n = 0; n < 5; ++n) acc[n] += yr[n];
  }
#pragma unroll
  for (int n = 0; n < 5; ++n) {
    acc[n] += __shfl_down(acc[n], 8, 16);
    acc[n] += __shfl_down(acc[n], 4, 16);
    acc[n] += __shfl_down(acc[n], 2, 16);
    acc[n] += __shfl_down(acc[n], 1, 16);
  }
  if (l == 0) {
#pragma unroll
    for (int n = 0; n < 5; ++n)
      out[(size_t)v * 5 + n] = acc[n] * inv + yz[(size_t)v * 10 + 5 + n] + b[n];
  }
}

// ---------------- launcher ----------------
extern "C" void kernel_launch(void* const* d_in, const int* in_sizes, int n_in,
                              void* d_out, int out_size, void* d_ws, size_t ws_size,
                              hipStream_t stream) {
  const float* x = (const float*)d_in[0];
  const int* ei = (const int*)d_in[1];
  const int N = in_sizes[0] / 768;
  const int E = in_sizes[1] / 2;
  const int* src = ei;
  const int* dst = ei + E;

  const float* Wl[5];
  const float* Wr[5];
  const float* bb[5];
  for (int l = 0; l < 5; ++l) {
    Wl[l] = (const float*)d_in[2 + 3 * l];
    Wr[l] = (const float*)d_in[3 + 3 * l];
    bb[l] = (const float*)d_in[4 + 3 * l];
  }

  char* w = (char*)d_ws;
  size_t off = 0;
  auto take = [&](size_t bytes) -> char* {
    char* p = w + off;
    off = (off + bytes + 255) & ~(size_t)255;
    return p;
  };
  // arenas (aliased over layer lifetime)
  unsigned short* ar1 = (unsigned short*)take((size_t)N * 768 * 2);   // xb -> C3
  unsigned short* ar2 = (unsigned short*)take((size_t)N * 768 * 2);   // aggb -> h2
  unsigned short* ar3 = (unsigned short*)take((size_t)N * 1536 * 2);  // h1 -> C4|h3|h4|yz5
  unsigned short* C2  = (unsigned short*)take((size_t)N * 1536 * 2);
  int* cnt  = (int*)take((size_t)N * 4);
  int* rp   = (int*)take((size_t)(N + 1) * 4);
  int* cur  = (int*)take((size_t)N * 4);
  int* col  = (int*)take((size_t)E * 4);
  const int nbChunks = (N + 1023) / 1024;
  int* bsum = (int*)take((size_t)(nbChunks + 1) * 4);
  unsigned short* WT1l = (unsigned short*)take((size_t)1536 * 768 * 2);
  unsigned short* WT1r = (unsigned short*)take((size_t)1536 * 768 * 2);
  unsigned short* WT2  = (unsigned short*)take((size_t)1536 * 1536 * 2);
  unsigned short* WT3  = (unsigned short*)take((size_t)768 * 768 * 2);
  unsigned short* WT4  = (unsigned short*)take((size_t)512 * 384 * 2);

  unsigned short* xb   = ar1;
  unsigned short* C3   = ar1;
  unsigned short* aggb = ar2;
  unsigned short* h2   = ar2;
  unsigned short* h1   = ar3;
  unsigned short* C4   = ar3;                                  // N x 512
  unsigned short* h3   = ar3 + (size_t)N * 512;                // N x 384
  unsigned short* h4   = ar3 + (size_t)N * (512 + 384);        // N x 256
  float*          yz5  = (float*)(ar3 + (size_t)N * (512 + 384 + 256)); // N x 10 f32

  const int M = N;
  const int Mt = (M + 255) / 256;          // 256-row tiles for the 8-phase GEMM

  // CSR build (scanB folded into scanC)
  hipMemsetAsync(cnt, 0, (size_t)N * 4, stream);
  gs_count_deg<<<(E + 255) / 256, 256, 0, stream>>>(dst, cnt, E);
  gs_scanA<<<nbChunks, 256, 0, stream>>>(cnt, rp, bsum, N);
  gs_scanC<<<(N + 256) / 256, 256, 0, stream>>>(rp, cur, bsum, N, nbChunks);
  gs_fill_csr<<<(E + 255) / 256, 256, 0, stream>>>(src, dst, cur, col, E);

  // conversions (all coalesced); batched transpose-pack (1 launch)
  gs_f32_to_bf16<<<((N * 768 / 4) + 255) / 256, 256, 0, stream>>>(x, xb, N * 768 / 4);
  TP8 tp;
  tp.t[0] = {Wl[0], WT1l, 768, 1536};
  tp.t[1] = {Wr[0], WT1r, 768, 1536};
  tp.t[2] = {Wl[1], WT2, 1536, 768};
  tp.t[3] = {Wr[1], WT2 + (size_t)768 * 1536, 1536, 768};
  tp.t[4] = {Wl[2], WT3, 768, 384};
  tp.t[5] = {Wr[2], WT3 + (size_t)384 * 768, 768, 384};
  tp.t[6] = {Wl[3], WT4, 384, 256};
  tp.t[7] = {Wr[3], WT4 + (size_t)256 * 384, 384, 256};
  gs_tpack8<<<dim3(48, 48, 8), dim3(32, 8), 0, stream>>>(tp);

  float* houtF = (float*)d_out;                 // [N,256] fp32
  float* out5  = (float*)d_out + (size_t)N * 256;

  // L1: agg-before (Fin 768 < Fout 1536), dual GEMM -> h1 (relu+bias)
  gs_agg_sliceT<4><<<dim3(N, 3), 64, 0, stream>>>(xb, 768, -1, rp, col, nullptr, aggb, nullptr, 768, 0);
  gs_gemm<<<Mt * 6, 512, 0, stream>>>(aggb, xb, WT1l, WT1r, bb[0], h1, M, 1536, 768, 1, Mt, 6);

  // L2: GEMM C2 = h1 @ [Wl2|Wr2]  (N x 1536), fused sliced agg over 768 -> h2
  gs_gemm<<<Mt * 6, 512, 0, stream>>>(h1, nullptr, WT2, nullptr, nullptr, C2, M, 1536, 1536, 0, Mt, 6);
  gs_agg_sliceT<4><<<dim3(N, 3), 64, 0, stream>>>(C2, 1536, 768, rp, col, bb[1], h2, nullptr, 768, 1);

  // L3: GEMM C3 = h2 @ [Wl3|Wr3]  (N x 768), fused sliced agg over 384 -> h3
  gs_gemm<<<Mt * 3, 512, 0, stream>>>(h2, nullptr, WT3, nullptr, nullptr, C3, M, 768, 768, 0, Mt, 3);
  gs_agg_sliceT<2><<<dim3(N, 3), 64, 0, stream>>>(C3, 768, 384, rp, col, bb[2], h3, nullptr, 384, 1);

  // L4: GEMM C4 = h3 @ [Wl4|Wr4]  (N x 512), fused sliced agg over 256 -> h4 (bf16) + d_out (fp32)
  gs_gemm<<<Mt * 2, 512, 0, stream>>>(h3, nullptr, WT4, nullptr, nullptr, C4, M, 512, 384, 0, Mt, 2);
  gs_agg_sliceT<4><<<dim3(N, 1), 64, 0, stream>>>(C4, 512, 256, rp, col, bb[3], h4, houtF, 256, 1);

  // L5: per-node dot -> yz5 [N,10] fp32 (4 nodes/block), 16-lane agg -> out
  gs_l5dot<<<(N + 3) / 4, 256, 0, stream>>>(h4, Wl[4], Wr[4], yz5, N);
  gs_l5agg<<<(N + 15) / 16, 256, 0, stream>>>(yz5, rp, col, bb[4], out5, N);
}